// Round 1
// baseline (2797.531 us; speedup 1.0000x reference)
//
#include <hip/hip_runtime.h>
#include <math.h>

#define BB 4
#define HH 4
#define NN 2048
#define DD 256
#define HDIM 64
#define NTOK (BB*NN)   // 8192

// ---------------------------------------------------------------------------
// Generic fp32 GEMM: C = A[M,K] @ W[K,Nc] + bias, tiled 64x64, 4x4 per thread.
// mode 0: row-major write to o0 (ldc), optional residual R (ldr) added.
// mode 1: QKV scatter (Nc=768): col c -> (h = (c/3)/64, d = (c/3)%64, s = c%3),
//         write to o0/o1/o2 as [B,H,N,HD].
// mode 2: head-split (Nc=256): col c -> (h = c/64, d = c%64), write o0 [B,H,N,HD].
// ---------------------------------------------------------------------------
__global__ __launch_bounds__(256) void gemm_bias(
    const float* __restrict__ A, int lda,
    const float* __restrict__ W, int ldw,
    const float* __restrict__ bias,
    int K, int mode,
    float* __restrict__ o0, float* __restrict__ o1, float* __restrict__ o2,
    int ldc, const float* __restrict__ R, int ldr)
{
    __shared__ __align__(16) float As[32][68];   // [k][m] (transposed A tile)
    __shared__ __align__(16) float Ws[32][68];   // [k][n]
    const int t  = threadIdx.x;
    const int m0 = blockIdx.y * 64, n0 = blockIdx.x * 64;
    const int r0 = (t >> 4) << 2, c0 = (t & 15) << 2;
    float acc[4][4] = {};

    for (int k0 = 0; k0 < K; k0 += 32) {
        // A tile: 64 rows x 32 cols, loaded as f4, stored transposed
        for (int f = t; f < 512; f += 256) {
            int r = f >> 3, kq = f & 7;
            float4 a = *(const float4*)&A[(size_t)(m0 + r) * lda + k0 + kq * 4];
            As[kq*4+0][r] = a.x; As[kq*4+1][r] = a.y;
            As[kq*4+2][r] = a.z; As[kq*4+3][r] = a.w;
        }
        // W tile: 32 rows x 64 cols
        for (int f = t; f < 512; f += 256) {
            int kk2 = f >> 4, nq = f & 15;
            *(float4*)&Ws[kk2][nq*4] =
                *(const float4*)&W[(size_t)(k0 + kk2) * ldw + n0 + nq * 4];
        }
        __syncthreads();
        #pragma unroll
        for (int kk = 0; kk < 32; kk++) {
            float4 av = *(const float4*)&As[kk][r0];
            float4 wv = *(const float4*)&Ws[kk][c0];
            float a4[4] = {av.x, av.y, av.z, av.w};
            float w4[4] = {wv.x, wv.y, wv.z, wv.w};
            #pragma unroll
            for (int i = 0; i < 4; i++)
                #pragma unroll
                for (int j = 0; j < 4; j++)
                    acc[i][j] += a4[i] * w4[j];
        }
        __syncthreads();
    }

    float bv[4] = {bias[n0+c0], bias[n0+c0+1], bias[n0+c0+2], bias[n0+c0+3]};

    if (mode == 0) {
        #pragma unroll
        for (int i = 0; i < 4; i++) {
            int row = m0 + r0 + i;
            float4 o;
            o.x = acc[i][0] + bv[0]; o.y = acc[i][1] + bv[1];
            o.z = acc[i][2] + bv[2]; o.w = acc[i][3] + bv[3];
            if (R) {
                float4 rv = *(const float4*)&R[(size_t)row * ldr + n0 + c0];
                o.x += rv.x; o.y += rv.y; o.z += rv.z; o.w += rv.w;
            }
            *(float4*)&o0[(size_t)row * ldc + n0 + c0] = o;
        }
    } else if (mode == 1) {
        #pragma unroll
        for (int i = 0; i < 4; i++) {
            int row = m0 + r0 + i;
            int b = row >> 11, n = row & (NN - 1);
            #pragma unroll
            for (int j = 0; j < 4; j++) {
                int cg  = n0 + c0 + j;
                int sel = cg % 3, rem = cg / 3;
                int d2 = rem & 63, h2 = rem >> 6;
                float* dst = (sel == 0) ? o0 : ((sel == 1) ? o1 : o2);
                dst[(((size_t)(b*HH + h2)) * NN + n) * HDIM + d2] = acc[i][j] + bv[j];
            }
        }
    } else {
        #pragma unroll
        for (int i = 0; i < 4; i++) {
            int row = m0 + r0 + i;
            int b = row >> 11, n = row & (NN - 1);
            #pragma unroll
            for (int j = 0; j < 4; j++) {
                int cg = n0 + c0 + j;
                int h2 = cg >> 6, d2 = cg & 63;
                o0[(((size_t)(b*HH + h2)) * NN + n) * HDIM + d2] = acc[i][j] + bv[j];
            }
        }
    }
}

// ---------------------------------------------------------------------------
// RoPE in place on t [B,H,N,HD]; enc [2,B,1,N,HD].
// out[2i]   = t[2i]*f0[2i]   - t[2i+1]*f1[2i]
// out[2i+1] = t[2i+1]*f0[2i+1] + t[2i]*f1[2i+1]
// ---------------------------------------------------------------------------
__global__ __launch_bounds__(256) void rope_k(float* __restrict__ tq,
                                              const float* __restrict__ enc)
{
    int i = blockIdx.x * 256 + threadIdx.x;       // pair index, 2^20 total
    int dp = (i & 31) * 2;
    int n  = (i >> 5) & (NN - 1);
    int h  = (i >> 16) & 3;
    int b  = i >> 18;
    size_t ti = (((size_t)(b*HH + h)) * NN + n) * HDIM + dp;
    size_t e  = ((size_t)b * NN + n) * HDIM + dp;
    const float* e0 = enc;
    const float* e1 = enc + (size_t)BB * NN * HDIM;
    float x0 = tq[ti], x1 = tq[ti + 1];
    tq[ti]     = x0 * e0[e]     - x1 * e1[e];
    tq[ti + 1] = x1 * e0[e + 1] + x0 * e1[e + 1];
}

// ---------------------------------------------------------------------------
// Flash attention fp32: Q,K,V [BH][N][HD]; O merged [B][N][D] (col = h*HD+d).
// Block = (64-query tile) x (one bh). Online softmax, P tile reuses Ks LDS.
// ---------------------------------------------------------------------------
__global__ __launch_bounds__(256) void flash_attn(
    const float* __restrict__ Q, const float* __restrict__ K,
    const float* __restrict__ V, float* __restrict__ O, float scale)
{
    __shared__ __align__(16) float Qs[64][68];
    __shared__ __align__(16) float Ks[64][68];   // also holds P after softmax
    __shared__ __align__(16) float Vs[64][68];
    __shared__ float red[64][17];
    __shared__ float mrow[64], lrow[64], arow[64], mnew[64];
    const int t  = threadIdx.x;
    const int bh = blockIdx.y;
    const int q0 = blockIdx.x * 64;
    const int r0 = (t >> 4) << 2, c0 = (t & 15) << 2;
    const float* Qb = Q + (size_t)bh * NN * HDIM;
    const float* Kb = K + (size_t)bh * NN * HDIM;
    const float* Vb = V + (size_t)bh * NN * HDIM;

    for (int f = t; f < 1024; f += 256) {
        int r = f >> 4, c4 = (f & 15) * 4;
        *(float4*)&Qs[r][c4] = *(const float4*)&Qb[(size_t)(q0 + r) * HDIM + c4];
    }
    if (t < 64) { mrow[t] = -1e30f; lrow[t] = 0.f; }
    float accO[4][4] = {};
    __syncthreads();

    for (int j0 = 0; j0 < NN; j0 += 64) {
        for (int f = t; f < 1024; f += 256) {
            int r = f >> 4, c4 = (f & 15) * 4;
            *(float4*)&Ks[r][c4] = *(const float4*)&Kb[(size_t)(j0 + r) * HDIM + c4];
            *(float4*)&Vs[r][c4] = *(const float4*)&Vb[(size_t)(j0 + r) * HDIM + c4];
        }
        __syncthreads();

        // S = scale * Q K^T  (4x4 per thread)
        float s[4][4] = {};
        #pragma unroll
        for (int kk = 0; kk < 64; kk += 4) {
            float4 qv[4], kv[4];
            #pragma unroll
            for (int i = 0; i < 4; i++) qv[i] = *(const float4*)&Qs[r0 + i][kk];
            #pragma unroll
            for (int j = 0; j < 4; j++) kv[j] = *(const float4*)&Ks[c0 + j][kk];
            #pragma unroll
            for (int i = 0; i < 4; i++)
                #pragma unroll
                for (int j = 0; j < 4; j++)
                    s[i][j] += qv[i].x*kv[j].x + qv[i].y*kv[j].y
                             + qv[i].z*kv[j].z + qv[i].w*kv[j].w;
        }
        #pragma unroll
        for (int i = 0; i < 4; i++) {
            float mx = -1e30f;
            #pragma unroll
            for (int j = 0; j < 4; j++) { s[i][j] *= scale; mx = fmaxf(mx, s[i][j]); }
            red[r0 + i][t & 15] = mx;
        }
        __syncthreads();
        if (t < 64) {
            float m = red[t][0];
            for (int jj = 1; jj < 16; jj++) m = fmaxf(m, red[t][jj]);
            float mo = mrow[t];
            float mn = fmaxf(mo, m);
            mnew[t] = mn; arow[t] = expf(mo - mn); mrow[t] = mn;
        }
        __syncthreads();
        // P = exp(S - mnew), stored into Ks; partial row sums
        #pragma unroll
        for (int i = 0; i < 4; i++) {
            float mi = mnew[r0 + i];
            float sum = 0.f;
            #pragma unroll
            for (int j = 0; j < 4; j++) {
                float p = expf(s[i][j] - mi);
                Ks[r0 + i][c0 + j] = p;
                sum += p;
            }
            red[r0 + i][t & 15] = sum;
        }
        __syncthreads();
        if (t < 64) {
            float ssum = 0.f;
            for (int jj = 0; jj < 16; jj++) ssum += red[t][jj];
            lrow[t] = lrow[t] * arow[t] + ssum;
        }
        // rescale O, accumulate P·V
        #pragma unroll
        for (int i = 0; i < 4; i++) {
            float a = arow[r0 + i];
            #pragma unroll
            for (int j = 0; j < 4; j++) accO[i][j] *= a;
        }
        #pragma unroll
        for (int jj = 0; jj < 64; jj += 4) {
            float4 pv[4], vv[4];
            #pragma unroll
            for (int i = 0; i < 4; i++) pv[i] = *(const float4*)&Ks[r0 + i][jj];
            #pragma unroll
            for (int jq = 0; jq < 4; jq++) vv[jq] = *(const float4*)&Vs[jj + jq][c0];
            #pragma unroll
            for (int i = 0; i < 4; i++) {
                accO[i][0] += pv[i].x*vv[0].x + pv[i].y*vv[1].x + pv[i].z*vv[2].x + pv[i].w*vv[3].x;
                accO[i][1] += pv[i].x*vv[0].y + pv[i].y*vv[1].y + pv[i].z*vv[2].y + pv[i].w*vv[3].y;
                accO[i][2] += pv[i].x*vv[0].z + pv[i].y*vv[1].z + pv[i].z*vv[2].z + pv[i].w*vv[3].z;
                accO[i][3] += pv[i].x*vv[0].w + pv[i].y*vv[1].w + pv[i].z*vv[2].w + pv[i].w*vv[3].w;
            }
        }
        __syncthreads();
    }

    const int b = bh >> 2, h = bh & 3;
    #pragma unroll
    for (int i = 0; i < 4; i++) {
        float inv = 1.f / lrow[r0 + i];
        float4 o;
        o.x = accO[i][0]*inv; o.y = accO[i][1]*inv;
        o.z = accO[i][2]*inv; o.w = accO[i][3]*inv;
        *(float4*)&O[((size_t)(b*NN + q0 + r0 + i)) * DD + h*HDIM + c0] = o;
    }
}

// ---------------------------------------------------------------------------
// Per-row (width 512) LayerNorm + exact GELU. One block per row.
// ---------------------------------------------------------------------------
__global__ __launch_bounds__(256) void ln_gelu(
    const float* __restrict__ in, const float* __restrict__ g,
    const float* __restrict__ be, float* __restrict__ out)
{
    __shared__ float r1[4], r2[4];
    const int t = threadIdx.x;
    const size_t row = blockIdx.x;
    const float* ip = in + row * 512;
    float x0 = ip[t], x1 = ip[t + 256];
    float s = x0 + x1, ss = x0*x0 + x1*x1;
    #pragma unroll
    for (int o = 32; o > 0; o >>= 1) { s += __shfl_down(s, o); ss += __shfl_down(ss, o); }
    if ((t & 63) == 0) { r1[t >> 6] = s; r2[t >> 6] = ss; }
    __syncthreads();
    float S  = r1[0] + r1[1] + r1[2] + r1[3];
    float SS = r2[0] + r2[1] + r2[2] + r2[3];
    float mean = S * (1.f/512.f);
    float var  = SS * (1.f/512.f) - mean*mean;
    float inv  = rsqrtf(var + 1e-5f);
    float* op = out + row * 512;
    float y0 = (x0 - mean) * inv * g[t]       + be[t];
    float y1 = (x1 - mean) * inv * g[t + 256] + be[t + 256];
    op[t]       = 0.5f * y0 * (1.f + erff(y0 * 0.70710678f));
    op[t + 256] = 0.5f * y1 * (1.f + erff(y1 * 0.70710678f));
}

// ---------------------------------------------------------------------------
// cat[row, 0:256] = src[row, :]
// ---------------------------------------------------------------------------
__global__ __launch_bounds__(256) void copy_cols(const float* __restrict__ src,
                                                 float* __restrict__ dst)
{
    int i = blockIdx.x * 256 + threadIdx.x;   // f4 index over 8192*64
    int row = i >> 6, c4 = (i & 63) * 4;
    *(float4*)&dst[(size_t)row * 512 + c4] = *(const float4*)&src[(size_t)row * 256 + c4];
}

// ---------------------------------------------------------------------------
extern "C" void kernel_launch(void* const* d_in, const int* in_sizes, int n_in,
                              void* d_out, int out_size, void* d_ws, size_t ws_size,
                              hipStream_t stream)
{
    const float* desc0 = (const float*)d_in[0];
    const float* desc1 = (const float*)d_in[1];
    const float* enc0  = (const float*)d_in[2];
    const float* enc1  = (const float*)d_in[3];
    const float* Wqkv  = (const float*)d_in[4];  const float* bqkv  = (const float*)d_in[5];
    const float* Wo_s  = (const float*)d_in[6];  const float* bo_s  = (const float*)d_in[7];
    const float* W1_s  = (const float*)d_in[8];  const float* b1_s  = (const float*)d_in[9];
    const float* g_s   = (const float*)d_in[10]; const float* be_s  = (const float*)d_in[11];
    const float* W2_s  = (const float*)d_in[12]; const float* b2_s  = (const float*)d_in[13];
    const float* Wqk_c = (const float*)d_in[14]; const float* bqk_c = (const float*)d_in[15];
    const float* Wv_c  = (const float*)d_in[16]; const float* bv_c  = (const float*)d_in[17];
    const float* Wo_c  = (const float*)d_in[18]; const float* bo_c  = (const float*)d_in[19];
    const float* W1_c  = (const float*)d_in[20]; const float* b1_c  = (const float*)d_in[21];
    const float* g_c   = (const float*)d_in[22]; const float* be_c  = (const float*)d_in[23];
    const float* W2_c  = (const float*)d_in[24]; const float* b2_c  = (const float*)d_in[25];

    float* ws = (float*)d_ws;
    const size_t S1 = (size_t)NTOK * DD;   // 2,097,152 floats
    float* qb  = ws;
    float* kb  = ws + S1;
    float* vb  = ws + 2*S1;
    float* msg = ws + 3*S1;
    float* cat = ws + 4*S1;   // 2*S1 floats
    float* hb  = ws + 6*S1;   // 2*S1 floats
    float* db0 = ws + 8*S1;
    float* db1 = ws + 9*S1;
    float* m0b = ws + 10*S1;
    float* m1b = ws + 11*S1;

    float* out0 = (float*)d_out;
    float* out1 = out0 + S1;

    dim3 blk(256);
    auto gemm = [&](const float* A, int lda, const float* W, int ldw, const float* bias,
                    int M, int K, int Nc, int mode, float* p0, float* p1, float* p2,
                    int ldc, const float* R, int ldr) {
        dim3 g(Nc / 64, M / 64);
        hipLaunchKernelGGL(gemm_bias, g, blk, 0, stream,
                           A, lda, W, ldw, bias, K, mode, p0, p1, p2, ldc, R, ldr);
    };

    // ---- self blocks (shared weights) ----
    for (int d = 0; d < 2; d++) {
        const float* x   = d ? desc1 : desc0;
        const float* enc = d ? enc1  : enc0;
        float* dout      = d ? db1   : db0;
        gemm(x, DD, Wqkv, 3*DD, bqkv, NTOK, DD, 3*DD, 1, qb, kb, vb, 0, nullptr, 0);
        hipLaunchKernelGGL(rope_k, dim3(4096), blk, 0, stream, qb, enc);
        hipLaunchKernelGGL(rope_k, dim3(4096), blk, 0, stream, kb, enc);
        hipLaunchKernelGGL(flash_attn, dim3(NN/64, BB*HH), blk, 0, stream,
                           qb, kb, vb, msg, 0.125f);
        hipLaunchKernelGGL(copy_cols, dim3(2048), blk, 0, stream, x, cat);
        gemm(msg, DD, Wo_s, DD, bo_s, NTOK, DD, DD, 0, cat + DD, nullptr, nullptr, 2*DD, nullptr, 0);
        gemm(cat, 2*DD, W1_s, 2*DD, b1_s, NTOK, 2*DD, 2*DD, 0, hb, nullptr, nullptr, 2*DD, nullptr, 0);
        hipLaunchKernelGGL(ln_gelu, dim3(NTOK), blk, 0, stream, hb, g_s, be_s, hb);
        gemm(hb, 2*DD, W2_s, DD, b2_s, NTOK, 2*DD, DD, 0, dout, nullptr, nullptr, DD, x, DD);
    }

    // ---- cross block ----
    // sim scale: both qk scaled by s^0.5 in ref => sim scaled by s=0.125; apply in flash.
    gemm(db0, DD, Wqk_c, DD, bqk_c, NTOK, DD, DD, 2, qb,  nullptr, nullptr, 0, nullptr, 0);
    gemm(db1, DD, Wqk_c, DD, bqk_c, NTOK, DD, DD, 2, kb,  nullptr, nullptr, 0, nullptr, 0);
    gemm(db0, DD, Wv_c,  DD, bv_c,  NTOK, DD, DD, 2, vb,  nullptr, nullptr, 0, nullptr, 0);
    gemm(db1, DD, Wv_c,  DD, bv_c,  NTOK, DD, DD, 2, msg, nullptr, nullptr, 0, nullptr, 0);
    // m0 = softmax(qk0·qk1^T)·v1 ; m1 = softmax(qk1·qk0^T)·v0
    hipLaunchKernelGGL(flash_attn, dim3(NN/64, BB*HH), blk, 0, stream, qb, kb, msg, m0b, 0.125f);
    hipLaunchKernelGGL(flash_attn, dim3(NN/64, BB*HH), blk, 0, stream, kb, qb, vb,  m1b, 0.125f);

    for (int d = 0; d < 2; d++) {
        const float* xres = d ? db1 : db0;
        const float* mm   = d ? m1b : m0b;
        float* oo         = d ? out1 : out0;
        hipLaunchKernelGGL(copy_cols, dim3(2048), blk, 0, stream, xres, cat);
        gemm(mm, DD, Wo_c, DD, bo_c, NTOK, DD, DD, 0, cat + DD, nullptr, nullptr, 2*DD, nullptr, 0);
        gemm(cat, 2*DD, W1_c, 2*DD, b1_c, NTOK, 2*DD, 2*DD, 0, hb, nullptr, nullptr, 2*DD, nullptr, 0);
        hipLaunchKernelGGL(ln_gelu, dim3(NTOK), blk, 0, stream, hb, g_c, be_c, hb);
        gemm(hb, 2*DD, W2_c, DD, b2_c, NTOK, 2*DD, DD, 0, oo, nullptr, nullptr, DD, xres, DD);
    }
}

// Round 2
// 1307.869 us; speedup vs baseline: 2.1390x; 2.1390x over previous
//
#include <hip/hip_runtime.h>
#include <math.h>

#define BB 4
#define HH 4
#define NN 2048
#define DD 256
#define HDIM 64
#define NTOK (BB*NN)   // 8192

typedef __attribute__((ext_vector_type(8))) __bf16 bf16x8;
typedef __attribute__((ext_vector_type(8))) unsigned short ushort8;
typedef __attribute__((ext_vector_type(4))) float floatx4;

union U8 { ushort8 u; bf16x8 b; };

__device__ __forceinline__ unsigned short f2bf(float x) {
    unsigned int u = __float_as_uint(x);
    u += 0x7FFF + ((u >> 16) & 1);
    return (unsigned short)(u >> 16);
}

// ---------------------------------------------------------------------------
// Generic fp32 GEMM: C = A[M,K] @ W[K,Nc] + bias, tiled 64x64, 4x4 per thread.
// mode 0: row-major write to o0 (ldc), optional residual R (ldr) added.
// mode 1: QKV scatter (Nc=768). mode 2: head-split (Nc=256).
// ---------------------------------------------------------------------------
__global__ __launch_bounds__(256) void gemm_bias(
    const float* __restrict__ A, int lda,
    const float* __restrict__ W, int ldw,
    const float* __restrict__ bias,
    int K, int mode,
    float* __restrict__ o0, float* __restrict__ o1, float* __restrict__ o2,
    int ldc, const float* __restrict__ R, int ldr)
{
    __shared__ __align__(16) float As[32][68];   // [k][m] (transposed A tile)
    __shared__ __align__(16) float Ws[32][68];   // [k][n]
    const int t  = threadIdx.x;
    const int m0 = blockIdx.y * 64, n0 = blockIdx.x * 64;
    const int r0 = (t >> 4) << 2, c0 = (t & 15) << 2;
    float acc[4][4] = {};

    for (int k0 = 0; k0 < K; k0 += 32) {
        for (int f = t; f < 512; f += 256) {
            int r = f >> 3, kq = f & 7;
            float4 a = *(const float4*)&A[(size_t)(m0 + r) * lda + k0 + kq * 4];
            As[kq*4+0][r] = a.x; As[kq*4+1][r] = a.y;
            As[kq*4+2][r] = a.z; As[kq*4+3][r] = a.w;
        }
        for (int f = t; f < 512; f += 256) {
            int kk2 = f >> 4, nq = f & 15;
            *(float4*)&Ws[kk2][nq*4] =
                *(const float4*)&W[(size_t)(k0 + kk2) * ldw + n0 + nq * 4];
        }
        __syncthreads();
        #pragma unroll
        for (int kk = 0; kk < 32; kk++) {
            float4 av = *(const float4*)&As[kk][r0];
            float4 wv = *(const float4*)&Ws[kk][c0];
            float a4[4] = {av.x, av.y, av.z, av.w};
            float w4[4] = {wv.x, wv.y, wv.z, wv.w};
            #pragma unroll
            for (int i = 0; i < 4; i++)
                #pragma unroll
                for (int j = 0; j < 4; j++)
                    acc[i][j] += a4[i] * w4[j];
        }
        __syncthreads();
    }

    float bv[4] = {bias[n0+c0], bias[n0+c0+1], bias[n0+c0+2], bias[n0+c0+3]};

    if (mode == 0) {
        #pragma unroll
        for (int i = 0; i < 4; i++) {
            int row = m0 + r0 + i;
            float4 o;
            o.x = acc[i][0] + bv[0]; o.y = acc[i][1] + bv[1];
            o.z = acc[i][2] + bv[2]; o.w = acc[i][3] + bv[3];
            if (R) {
                float4 rv = *(const float4*)&R[(size_t)row * ldr + n0 + c0];
                o.x += rv.x; o.y += rv.y; o.z += rv.z; o.w += rv.w;
            }
            *(float4*)&o0[(size_t)row * ldc + n0 + c0] = o;
        }
    } else if (mode == 1) {
        #pragma unroll
        for (int i = 0; i < 4; i++) {
            int row = m0 + r0 + i;
            int b = row >> 11, n = row & (NN - 1);
            #pragma unroll
            for (int j = 0; j < 4; j++) {
                int cg  = n0 + c0 + j;
                int sel = cg % 3, rem = cg / 3;
                int d2 = rem & 63, h2 = rem >> 6;
                float* dst = (sel == 0) ? o0 : ((sel == 1) ? o1 : o2);
                dst[(((size_t)(b*HH + h2)) * NN + n) * HDIM + d2] = acc[i][j] + bv[j];
            }
        }
    } else {
        #pragma unroll
        for (int i = 0; i < 4; i++) {
            int row = m0 + r0 + i;
            int b = row >> 11, n = row & (NN - 1);
            #pragma unroll
            for (int j = 0; j < 4; j++) {
                int cg = n0 + c0 + j;
                int h2 = cg >> 6, d2 = cg & 63;
                o0[(((size_t)(b*HH + h2)) * NN + n) * HDIM + d2] = acc[i][j] + bv[j];
            }
        }
    }
}

// ---------------------------------------------------------------------------
// RoPE in place on t [B,H,N,HD]; enc [2,B,1,N,HD].
// ---------------------------------------------------------------------------
__global__ __launch_bounds__(256) void rope_k(float* __restrict__ tq,
                                              const float* __restrict__ enc)
{
    int i = blockIdx.x * 256 + threadIdx.x;       // pair index, 2^20 total
    int dp = (i & 31) * 2;
    int n  = (i >> 5) & (NN - 1);
    int h  = (i >> 16) & 3;
    int b  = i >> 18;
    size_t ti = (((size_t)(b*HH + h)) * NN + n) * HDIM + dp;
    size_t e  = ((size_t)b * NN + n) * HDIM + dp;
    const float* e0 = enc;
    const float* e1 = enc + (size_t)BB * NN * HDIM;
    float x0 = tq[ti], x1 = tq[ti + 1];
    tq[ti]     = x0 * e0[e]     - x1 * e1[e];
    tq[ti + 1] = x1 * e0[e + 1] + x0 * e1[e + 1];
}

// ---------------------------------------------------------------------------
// MFMA bf16 flash attention: Q,K,V fp32 [BH][N][HD]; O merged [B][N][D].
// Block = 256 thr = 4 waves; 64 Q-rows per block (16 per wave); 64-key tiles.
// ---------------------------------------------------------------------------
__global__ __launch_bounds__(256) void flash_attn(
    const float* __restrict__ Q, const float* __restrict__ K,
    const float* __restrict__ V, float* __restrict__ O, float scale)
{
    __shared__ __align__(16) unsigned short Ks[64 * 72];   // [key][hd] bf16
    __shared__ __align__(16) unsigned short Vt[64 * 72];   // [hd][key] bf16
    __shared__ __align__(16) unsigned short Ps[4][16 * 72];// per-wave P, [q][key]

    const int t    = threadIdx.x;
    const int w    = t >> 6;
    const int lane = t & 63;
    const int quad = lane >> 4;
    const int l15  = lane & 15;
    const int bh   = blockIdx.y;
    const int q0   = blockIdx.x * 64;

    const float* Qb = Q + (size_t)bh * NN * HDIM;
    const float* Kb = K + (size_t)bh * NN * HDIM;
    const float* Vb = V + (size_t)bh * NN * HDIM;

    // --- Q fragments (A-layout), scaled by `scale`, kept in registers ---
    const int qrow = q0 + w * 16 + l15;
    bf16x8 qf0, qf1;
    {
        U8 x0, x1;
        const float* qp = &Qb[(size_t)qrow * HDIM + quad * 8];
        #pragma unroll
        for (int j = 0; j < 8; j++) x0.u[j] = f2bf(qp[j] * scale);
        const float* qp1 = qp + 32;
        #pragma unroll
        for (int j = 0; j < 8; j++) x1.u[j] = f2bf(qp1[j] * scale);
        qf0 = x0.b; qf1 = x1.b;
    }

    floatx4 o[4];
    #pragma unroll
    for (int c = 0; c < 4; c++) o[c] = (floatx4){0.f, 0.f, 0.f, 0.f};
    float m4[4] = {-1e30f, -1e30f, -1e30f, -1e30f};
    float l4[4] = {0.f, 0.f, 0.f, 0.f};

    for (int j0 = 0; j0 < NN; j0 += 64) {
        // ---- stage K (row-major) and V (transposed) as bf16 ----
        #pragma unroll
        for (int f = t; f < 1024; f += 256) {
            int r = f >> 4, c = (f & 15) * 4;
            float4 kv = *(const float4*)&Kb[(size_t)(j0 + r) * HDIM + c];
            ushort4 kw = { f2bf(kv.x), f2bf(kv.y), f2bf(kv.z), f2bf(kv.w) };
            *(ushort4*)&Ks[r * 72 + c] = kw;
            float4 vv = *(const float4*)&Vb[(size_t)(j0 + r) * HDIM + c];
            Vt[(c + 0) * 72 + r] = f2bf(vv.x);
            Vt[(c + 1) * 72 + r] = f2bf(vv.y);
            Vt[(c + 2) * 72 + r] = f2bf(vv.z);
            Vt[(c + 3) * 72 + r] = f2bf(vv.w);
        }
        __syncthreads();

        // ---- S = (scale*Q) K^T : 4 tiles of 16x16, each 2 MFMAs over HD ----
        floatx4 s[4];
        #pragma unroll
        for (int t4 = 0; t4 < 4; t4++) {
            U8 k0, k1;
            k0.u = *(const ushort8*)&Ks[(t4 * 16 + l15) * 72 + quad * 8];
            k1.u = *(const ushort8*)&Ks[(t4 * 16 + l15) * 72 + 32 + quad * 8];
            floatx4 z = (floatx4){0.f, 0.f, 0.f, 0.f};
            z = __builtin_amdgcn_mfma_f32_16x16x32_bf16(qf0, k0.b, z, 0, 0, 0);
            z = __builtin_amdgcn_mfma_f32_16x16x32_bf16(qf1, k1.b, z, 0, 0, 0);
            s[t4] = z;
        }

        // ---- online softmax (rows = quad*4+reg, cols = lane&15 per tile) ----
        float al[4];
        #pragma unroll
        for (int r = 0; r < 4; r++) {
            float mx = fmaxf(fmaxf(s[0][r], s[1][r]), fmaxf(s[2][r], s[3][r]));
            mx = fmaxf(mx, __shfl_xor(mx, 1, 64));
            mx = fmaxf(mx, __shfl_xor(mx, 2, 64));
            mx = fmaxf(mx, __shfl_xor(mx, 4, 64));
            mx = fmaxf(mx, __shfl_xor(mx, 8, 64));
            float mn = fmaxf(m4[r], mx);
            al[r] = __expf(m4[r] - mn);
            m4[r] = mn;
            float p0 = __expf(s[0][r] - mn);
            float p1 = __expf(s[1][r] - mn);
            float p2 = __expf(s[2][r] - mn);
            float p3 = __expf(s[3][r] - mn);
            s[0][r] = p0; s[1][r] = p1; s[2][r] = p2; s[3][r] = p3;
            float rs = p0 + p1 + p2 + p3;
            rs += __shfl_xor(rs, 1, 64);
            rs += __shfl_xor(rs, 2, 64);
            rs += __shfl_xor(rs, 4, 64);
            rs += __shfl_xor(rs, 8, 64);
            l4[r] = l4[r] * al[r] + rs;
            // write P row to per-wave LDS (C-layout -> A-layout round trip)
            #pragma unroll
            for (int t4 = 0; t4 < 4; t4++)
                Ps[w][(quad * 4 + r) * 72 + t4 * 16 + l15] = f2bf(s[t4][r]);
        }
        // rescale O
        #pragma unroll
        for (int c = 0; c < 4; c++)
            #pragma unroll
            for (int r = 0; r < 4; r++) o[c][r] *= al[r];

        // ---- O += P V : 2 K-chunks of 32 keys x 4 hd chunks ----
        #pragma unroll
        for (int kc = 0; kc < 2; kc++) {
            U8 pf;
            pf.u = *(const ushort8*)&Ps[w][l15 * 72 + kc * 32 + quad * 8];
            #pragma unroll
            for (int c = 0; c < 4; c++) {
                U8 vf;
                vf.u = *(const ushort8*)&Vt[(c * 16 + l15) * 72 + kc * 32 + quad * 8];
                o[c] = __builtin_amdgcn_mfma_f32_16x16x32_bf16(pf.b, vf.b, o[c], 0, 0, 0);
            }
        }
        __syncthreads();
    }

    // ---- epilogue: normalize, write merged [B][N][D] ----
    const int b = bh >> 2, h = bh & 3;
    #pragma unroll
    for (int r = 0; r < 4; r++) {
        float inv = 1.f / l4[r];
        int q = q0 + w * 16 + quad * 4 + r;
        #pragma unroll
        for (int c = 0; c < 4; c++)
            O[((size_t)(b * NN + q)) * DD + h * HDIM + c * 16 + l15] = o[c][r] * inv;
    }
}

// ---------------------------------------------------------------------------
// Per-row (width 512) LayerNorm + exact GELU. One block per row.
// ---------------------------------------------------------------------------
__global__ __launch_bounds__(256) void ln_gelu(
    const float* __restrict__ in, const float* __restrict__ g,
    const float* __restrict__ be, float* __restrict__ out)
{
    __shared__ float r1[4], r2[4];
    const int t = threadIdx.x;
    const size_t row = blockIdx.x;
    const float* ip = in + row * 512;
    float x0 = ip[t], x1 = ip[t + 256];
    float s = x0 + x1, ss = x0*x0 + x1*x1;
    #pragma unroll
    for (int o = 32; o > 0; o >>= 1) { s += __shfl_down(s, o); ss += __shfl_down(ss, o); }
    if ((t & 63) == 0) { r1[t >> 6] = s; r2[t >> 6] = ss; }
    __syncthreads();
    float S  = r1[0] + r1[1] + r1[2] + r1[3];
    float SS = r2[0] + r2[1] + r2[2] + r2[3];
    float mean = S * (1.f/512.f);
    float var  = SS * (1.f/512.f) - mean*mean;
    float inv  = rsqrtf(var + 1e-5f);
    float* op = out + row * 512;
    float y0 = (x0 - mean) * inv * g[t]       + be[t];
    float y1 = (x1 - mean) * inv * g[t + 256] + be[t + 256];
    op[t]       = 0.5f * y0 * (1.f + erff(y0 * 0.70710678f));
    op[t + 256] = 0.5f * y1 * (1.f + erff(y1 * 0.70710678f));
}

// ---------------------------------------------------------------------------
// cat[row, 0:256] = src[row, :]
// ---------------------------------------------------------------------------
__global__ __launch_bounds__(256) void copy_cols(const float* __restrict__ src,
                                                 float* __restrict__ dst)
{
    int i = blockIdx.x * 256 + threadIdx.x;   // f4 index over 8192*64
    int row = i >> 6, c4 = (i & 63) * 4;
    *(float4*)&dst[(size_t)row * 512 + c4] = *(const float4*)&src[(size_t)row * 256 + c4];
}

// ---------------------------------------------------------------------------
extern "C" void kernel_launch(void* const* d_in, const int* in_sizes, int n_in,
                              void* d_out, int out_size, void* d_ws, size_t ws_size,
                              hipStream_t stream)
{
    const float* desc0 = (const float*)d_in[0];
    const float* desc1 = (const float*)d_in[1];
    const float* enc0  = (const float*)d_in[2];
    const float* enc1  = (const float*)d_in[3];
    const float* Wqkv  = (const float*)d_in[4];  const float* bqkv  = (const float*)d_in[5];
    const float* Wo_s  = (const float*)d_in[6];  const float* bo_s  = (const float*)d_in[7];
    const float* W1_s  = (const float*)d_in[8];  const float* b1_s  = (const float*)d_in[9];
    const float* g_s   = (const float*)d_in[10]; const float* be_s  = (const float*)d_in[11];
    const float* W2_s  = (const float*)d_in[12]; const float* b2_s  = (const float*)d_in[13];
    const float* Wqk_c = (const float*)d_in[14]; const float* bqk_c = (const float*)d_in[15];
    const float* Wv_c  = (const float*)d_in[16]; const float* bv_c  = (const float*)d_in[17];
    const float* Wo_c  = (const float*)d_in[18]; const float* bo_c  = (const float*)d_in[19];
    const float* W1_c  = (const float*)d_in[20]; const float* b1_c  = (const float*)d_in[21];
    const float* g_c   = (const float*)d_in[22]; const float* be_c  = (const float*)d_in[23];
    const float* W2_c  = (const float*)d_in[24]; const float* b2_c  = (const float*)d_in[25];

    float* ws = (float*)d_ws;
    const size_t S1 = (size_t)NTOK * DD;   // 2,097,152 floats
    float* qb  = ws;
    float* kb  = ws + S1;
    float* vb  = ws + 2*S1;
    float* msg = ws + 3*S1;
    float* cat = ws + 4*S1;   // 2*S1 floats
    float* hb  = ws + 6*S1;   // 2*S1 floats
    float* db0 = ws + 8*S1;
    float* db1 = ws + 9*S1;
    float* m0b = ws + 10*S1;
    float* m1b = ws + 11*S1;

    float* out0 = (float*)d_out;
    float* out1 = out0 + S1;

    dim3 blk(256);
    auto gemm = [&](const float* A, int lda, const float* W, int ldw, const float* bias,
                    int M, int K, int Nc, int mode, float* p0, float* p1, float* p2,
                    int ldc, const float* R, int ldr) {
        dim3 g(Nc / 64, M / 64);
        hipLaunchKernelGGL(gemm_bias, g, blk, 0, stream,
                           A, lda, W, ldw, bias, K, mode, p0, p1, p2, ldc, R, ldr);
    };

    // ---- self blocks (shared weights) ----
    for (int d = 0; d < 2; d++) {
        const float* x   = d ? desc1 : desc0;
        const float* enc = d ? enc1  : enc0;
        float* dout      = d ? db1   : db0;
        gemm(x, DD, Wqkv, 3*DD, bqkv, NTOK, DD, 3*DD, 1, qb, kb, vb, 0, nullptr, 0);
        hipLaunchKernelGGL(rope_k, dim3(4096), blk, 0, stream, qb, enc);
        hipLaunchKernelGGL(rope_k, dim3(4096), blk, 0, stream, kb, enc);
        hipLaunchKernelGGL(flash_attn, dim3(NN/64, BB*HH), blk, 0, stream,
                           qb, kb, vb, msg, 0.125f);
        hipLaunchKernelGGL(copy_cols, dim3(2048), blk, 0, stream, x, cat);
        gemm(msg, DD, Wo_s, DD, bo_s, NTOK, DD, DD, 0, cat + DD, nullptr, nullptr, 2*DD, nullptr, 0);
        gemm(cat, 2*DD, W1_s, 2*DD, b1_s, NTOK, 2*DD, 2*DD, 0, hb, nullptr, nullptr, 2*DD, nullptr, 0);
        hipLaunchKernelGGL(ln_gelu, dim3(NTOK), blk, 0, stream, hb, g_s, be_s, hb);
        gemm(hb, 2*DD, W2_s, DD, b2_s, NTOK, 2*DD, DD, 0, dout, nullptr, nullptr, DD, x, DD);
    }

    // ---- cross block ----
    gemm(db0, DD, Wqk_c, DD, bqk_c, NTOK, DD, DD, 2, qb,  nullptr, nullptr, 0, nullptr, 0);
    gemm(db1, DD, Wqk_c, DD, bqk_c, NTOK, DD, DD, 2, kb,  nullptr, nullptr, 0, nullptr, 0);
    gemm(db0, DD, Wv_c,  DD, bv_c,  NTOK, DD, DD, 2, vb,  nullptr, nullptr, 0, nullptr, 0);
    gemm(db1, DD, Wv_c,  DD, bv_c,  NTOK, DD, DD, 2, msg, nullptr, nullptr, 0, nullptr, 0);
    hipLaunchKernelGGL(flash_attn, dim3(NN/64, BB*HH), blk, 0, stream, qb, kb, msg, m0b, 0.125f);
    hipLaunchKernelGGL(flash_attn, dim3(NN/64, BB*HH), blk, 0, stream, kb, qb, vb,  m1b, 0.125f);

    for (int d = 0; d < 2; d++) {
        const float* xres = d ? db1 : db0;
        const float* mm   = d ? m1b : m0b;
        float* oo         = d ? out1 : out0;
        hipLaunchKernelGGL(copy_cols, dim3(2048), blk, 0, stream, xres, cat);
        gemm(mm, DD, Wo_c, DD, bo_c, NTOK, DD, DD, 0, cat + DD, nullptr, nullptr, 2*DD, nullptr, 0);
        gemm(cat, 2*DD, W1_c, 2*DD, b1_c, NTOK, 2*DD, 2*DD, 0, hb, nullptr, nullptr, 2*DD, nullptr, 0);
        hipLaunchKernelGGL(ln_gelu, dim3(NTOK), blk, 0, stream, hb, g_c, be_c, hb);
        gemm(hb, 2*DD, W2_c, DD, b2_c, NTOK, 2*DD, DD, 0, oo, nullptr, nullptr, DD, xres, DD);
    }
}

// Round 3
// 679.665 us; speedup vs baseline: 4.1160x; 1.9243x over previous
//
#include <hip/hip_runtime.h>
#include <math.h>

#define BB 4
#define HH 4
#define NN 2048
#define DD 256
#define HDIM 64
#define NTOK 8192
#define NTOK2 16384

typedef __attribute__((ext_vector_type(8))) __bf16 bf16x8;
typedef __attribute__((ext_vector_type(8))) unsigned short ushort8;
typedef __attribute__((ext_vector_type(4))) float floatx4;

union U8 { ushort8 u; bf16x8 b; };

__device__ __forceinline__ unsigned short f2bf(float x) {
    unsigned int u = __float_as_uint(x);
    u += 0x7FFF + ((u >> 16) & 1);
    return (unsigned short)(u >> 16);
}
__device__ __forceinline__ float bf2f(unsigned short u) {
    return __uint_as_float(((unsigned int)u) << 16);
}

// ---------------------------------------------------------------------------
// Weight transpose+convert: W[K][N] f32 -> Wt[N][K] bf16.  One dispatch, 9 segs.
// ---------------------------------------------------------------------------
struct WTab {
    const float* w[9];
    unsigned short* o[9];
    int K[9];
    int N[9];
    int t0[10];
};

__global__ __launch_bounds__(256) void wtrans(WTab tab)
{
    __shared__ float lds[32][33];
    const int t = threadIdx.x;
    int bid = blockIdx.x;
    int s = 0;
    while (bid >= tab.t0[s + 1]) s++;
    const int ti = bid - tab.t0[s];
    const int K = tab.K[s], N = tab.N[s];
    const int tx = ti % (N / 32), ty = ti / (N / 32);
    const int k0 = ty * 32, n0 = tx * 32;
    const float* W = tab.w[s];
    unsigned short* Wt = tab.o[s];

    {
        int r = t >> 3, c = (t & 7) * 4;
        float4 a = *(const float4*)&W[(size_t)(k0 + r) * N + n0 + c];
        lds[r][c] = a.x; lds[r][c+1] = a.y; lds[r][c+2] = a.z; lds[r][c+3] = a.w;
    }
    __syncthreads();
    {
        int n = t >> 3, kq = (t & 7) * 4;
        ushort4 p;
        p.x = f2bf(lds[kq+0][n]); p.y = f2bf(lds[kq+1][n]);
        p.z = f2bf(lds[kq+2][n]); p.w = f2bf(lds[kq+3][n]);
        *(ushort4*)&Wt[(size_t)(n0 + n) * K + k0 + kq] = p;
    }
}

// ---------------------------------------------------------------------------
// bf16 MFMA GEMM: C[M=16384][N] = A @ Wt^T + bias.  Tile 128x64, 4 waves.
// A: two pointers (rows <8192 -> A0, else A1), bf16 or f32 (a_f32).
// Wt: [N][K] bf16 (pre-transposed).
// mode 0: f32 row-major (outF, ldc)
// mode 1: bf16 row-major (outH0, ldc)
// mode 2: bf16 head scatter [32][2048][64]  (outH0)
// mode 3: bf16 qkv scatter -> outH0/outH1/outH2
// mode 4: f32 out = acc+bias+R (R0/R1), ldc=256, + optional bf16 copy outH0
// ---------------------------------------------------------------------------
__global__ __launch_bounds__(256) void gemm_mfma(
    const void* A0v, const void* A1v, int lda, int a_f32,
    const unsigned short* __restrict__ Wt, int K,
    const float* __restrict__ bias, int mode,
    float* outF, unsigned short* outH0, unsigned short* outH1, unsigned short* outH2,
    int ldc, const float* R0, const float* R1)
{
    __shared__ __align__(16) unsigned short As[128 * 40];
    __shared__ __align__(16) unsigned short Bs[64 * 40];
    const int t = threadIdx.x;
    const int w = t >> 6, lane = t & 63, quad = lane >> 4, l15 = lane & 15;
    const int m0 = blockIdx.y * 128, n0 = blockIdx.x * 64;
    const int mside = (m0 >= 8192) ? 1 : 0;
    const int mrow0 = m0 & 8191;
    const float* Af = (const float*)(mside ? A1v : A0v);
    const unsigned short* Ah = (const unsigned short*)(mside ? A1v : A0v);

    floatx4 acc[4][2];
    #pragma unroll
    for (int i = 0; i < 4; i++)
        #pragma unroll
        for (int j = 0; j < 2; j++) acc[i][j] = (floatx4){0.f, 0.f, 0.f, 0.f};

    for (int k0 = 0; k0 < K; k0 += 32) {
        if (a_f32) {
            #pragma unroll
            for (int f = t; f < 1024; f += 256) {
                int r = f >> 3, ch = (f & 7) * 4;
                float4 a = *(const float4*)&Af[(size_t)(mrow0 + r) * lda + k0 + ch];
                ushort4 p = { f2bf(a.x), f2bf(a.y), f2bf(a.z), f2bf(a.w) };
                *(ushort4*)&As[r * 40 + ch] = p;
            }
        } else {
            #pragma unroll
            for (int f = t; f < 512; f += 256) {
                int r = f >> 2, ch = (f & 3) * 8;
                *(ushort8*)&As[r * 40 + ch] =
                    *(const ushort8*)&Ah[(size_t)(mrow0 + r) * lda + k0 + ch];
            }
        }
        {
            int r = t >> 2, ch = (t & 3) * 8;
            *(ushort8*)&Bs[r * 40 + ch] =
                *(const ushort8*)&Wt[(size_t)(n0 + r) * K + k0 + ch];
        }
        __syncthreads();
        U8 af[4], bf[2];
        #pragma unroll
        for (int i = 0; i < 4; i++)
            af[i].u = *(const ushort8*)&As[((w >> 1) * 64 + i * 16 + l15) * 40 + quad * 8];
        #pragma unroll
        for (int j = 0; j < 2; j++)
            bf[j].u = *(const ushort8*)&Bs[((w & 1) * 32 + j * 16 + l15) * 40 + quad * 8];
        #pragma unroll
        for (int i = 0; i < 4; i++)
            #pragma unroll
            for (int j = 0; j < 2; j++)
                acc[i][j] = __builtin_amdgcn_mfma_f32_16x16x32_bf16(af[i].b, bf[j].b, acc[i][j], 0, 0, 0);
        __syncthreads();
    }

    // epilogue
    const int rowb = m0 + (w >> 1) * 64;
    #pragma unroll
    for (int i = 0; i < 4; i++) {
        #pragma unroll
        for (int j = 0; j < 2; j++) {
            int col = n0 + (w & 1) * 32 + j * 16 + l15;
            float bv = bias[col];
            #pragma unroll
            for (int r = 0; r < 4; r++) {
                int grow = rowb + i * 16 + quad * 4 + r;
                float v = acc[i][j][r] + bv;
                if (mode == 0) {
                    outF[(size_t)grow * ldc + col] = v;
                } else if (mode == 1) {
                    outH0[(size_t)grow * ldc + col] = f2bf(v);
                } else if (mode == 2) {
                    int h = col >> 6, d = col & 63;
                    int ds = grow >> 13, b = (grow >> 11) & 3, n = grow & 2047;
                    int bh = ds * 16 + b * 4 + h;
                    outH0[((size_t)bh * NN + n) * HDIM + d] = f2bf(v);
                } else if (mode == 3) {
                    int sel = col % 3, cc = col / 3;
                    int h = cc >> 6, d = cc & 63;
                    int ds = grow >> 13, b = (grow >> 11) & 3, n = grow & 2047;
                    int bh = ds * 16 + b * 4 + h;
                    unsigned short* dst = (sel == 0) ? outH0 : ((sel == 1) ? outH1 : outH2);
                    dst[((size_t)bh * NN + n) * HDIM + d] = f2bf(v);
                } else {
                    const float* R = mside ? R1 : R0;
                    float vv = v + R[(size_t)(grow & 8191) * 256 + col];
                    outF[(size_t)grow * 256 + col] = vv;
                    if (outH0) outH0[(size_t)grow * 256 + col] = f2bf(vv);
                }
            }
        }
    }
}

// ---------------------------------------------------------------------------
// RoPE in place on qb and kb (bf16 [32][2048][64]); enc0/enc1 f32 [2,B,1,N,HD].
// ---------------------------------------------------------------------------
__global__ __launch_bounds__(256) void rope_k(unsigned short* __restrict__ qb,
                                              unsigned short* __restrict__ kb,
                                              const float* __restrict__ enc0,
                                              const float* __restrict__ enc1)
{
    int i = blockIdx.x * 256 + threadIdx.x;     // 2^22 pair slots
    int dp = (i & 31) * 2;
    int n  = (i >> 5) & (NN - 1);
    int h  = (i >> 16) & 3;
    int b  = (i >> 18) & 3;
    int ds = (i >> 20) & 1;
    int bf = (i >> 21) & 1;
    unsigned short* tq = (bf ? kb : qb) +
        (((size_t)(ds * 16 + b * 4 + h)) * NN + n) * HDIM + dp;
    const float* e0 = (ds ? enc1 : enc0) + ((size_t)b * NN + n) * HDIM + dp;
    const float* e1 = e0 + (size_t)BB * NN * HDIM;
    float x0 = bf2f(tq[0]), x1 = bf2f(tq[1]);
    float y0 = x0 * e0[0] - x1 * e1[0];
    float y1 = x1 * e0[1] + x0 * e1[1];
    tq[0] = f2bf(y0); tq[1] = f2bf(y1);
}

// ---------------------------------------------------------------------------
// MFMA bf16 flash attention, bf16 in/out.  Q,K,V: [32][2048][64] bf16.
// KV head index = bh ^ kvx (kvx=0 self, 16 cross).  O: bf16 [16384][256].
// ---------------------------------------------------------------------------
__global__ __launch_bounds__(256) void flash_attn(
    const unsigned short* __restrict__ Q, const unsigned short* __restrict__ K,
    const unsigned short* __restrict__ V, unsigned short* __restrict__ O,
    int kvx, float scale)
{
    __shared__ __align__(16) unsigned short Ks[64 * 72];    // [key][hd]
    __shared__ __align__(16) unsigned short Vt[64 * 72];    // [hd][key]
    __shared__ __align__(16) unsigned short Ps[4][16 * 72]; // per-wave P [q][key]

    const int t    = threadIdx.x;
    const int w    = t >> 6;
    const int lane = t & 63;
    const int quad = lane >> 4;
    const int l15  = lane & 15;
    const int bh   = blockIdx.y;
    const int kbh  = bh ^ kvx;
    const int q0   = blockIdx.x * 64;

    const unsigned short* Qb = Q + (size_t)bh  * NN * HDIM;
    const unsigned short* Kb = K + (size_t)kbh * NN * HDIM;
    const unsigned short* Vb = V + (size_t)kbh * NN * HDIM;

    // Q fragments (A-layout), scale folded (exact for 2^-3)
    const int qrow = q0 + w * 16 + l15;
    bf16x8 qf0, qf1;
    {
        U8 r0, r1, x0, x1;
        r0.u = *(const ushort8*)&Qb[(size_t)qrow * HDIM + quad * 8];
        r1.u = *(const ushort8*)&Qb[(size_t)qrow * HDIM + 32 + quad * 8];
        #pragma unroll
        for (int j = 0; j < 8; j++) {
            x0.u[j] = f2bf(bf2f(r0.u[j]) * scale);
            x1.u[j] = f2bf(bf2f(r1.u[j]) * scale);
        }
        qf0 = x0.b; qf1 = x1.b;
    }

    floatx4 o[4];
    #pragma unroll
    for (int c = 0; c < 4; c++) o[c] = (floatx4){0.f, 0.f, 0.f, 0.f};
    float m4[4] = {-1e30f, -1e30f, -1e30f, -1e30f};
    float l4[4] = {0.f, 0.f, 0.f, 0.f};

    for (int j0 = 0; j0 < NN; j0 += 64) {
        // stage K rows (pure copy)
        #pragma unroll
        for (int f = t; f < 512; f += 256) {
            int r = f >> 3, ch = (f & 7) * 8;
            *(ushort8*)&Ks[r * 72 + ch] =
                *(const ushort8*)&Kb[(size_t)(j0 + r) * HDIM + ch];
        }
        // stage V transposed: paired-key b32 writes (conflict-free)
        #pragma unroll
        for (int f = t; f < 512; f += 256) {
            int kp = f & 31, c4 = (f >> 5) * 4;
            ushort4 v0 = *(const ushort4*)&Vb[(size_t)(j0 + 2 * kp) * HDIM + c4];
            ushort4 v1 = *(const ushort4*)&Vb[(size_t)(j0 + 2 * kp + 1) * HDIM + c4];
            *(unsigned int*)&Vt[(c4 + 0) * 72 + 2 * kp] = (unsigned int)v0.x | ((unsigned int)v1.x << 16);
            *(unsigned int*)&Vt[(c4 + 1) * 72 + 2 * kp] = (unsigned int)v0.y | ((unsigned int)v1.y << 16);
            *(unsigned int*)&Vt[(c4 + 2) * 72 + 2 * kp] = (unsigned int)v0.z | ((unsigned int)v1.z << 16);
            *(unsigned int*)&Vt[(c4 + 3) * 72 + 2 * kp] = (unsigned int)v0.w | ((unsigned int)v1.w << 16);
        }
        __syncthreads();

        // S = (scale*Q) K^T
        floatx4 s[4];
        #pragma unroll
        for (int t4 = 0; t4 < 4; t4++) {
            U8 k0, k1;
            k0.u = *(const ushort8*)&Ks[(t4 * 16 + l15) * 72 + quad * 8];
            k1.u = *(const ushort8*)&Ks[(t4 * 16 + l15) * 72 + 32 + quad * 8];
            floatx4 z = (floatx4){0.f, 0.f, 0.f, 0.f};
            z = __builtin_amdgcn_mfma_f32_16x16x32_bf16(qf0, k0.b, z, 0, 0, 0);
            z = __builtin_amdgcn_mfma_f32_16x16x32_bf16(qf1, k1.b, z, 0, 0, 0);
            s[t4] = z;
        }

        // online softmax
        float al[4];
        #pragma unroll
        for (int r = 0; r < 4; r++) {
            float mx = fmaxf(fmaxf(s[0][r], s[1][r]), fmaxf(s[2][r], s[3][r]));
            mx = fmaxf(mx, __shfl_xor(mx, 1, 64));
            mx = fmaxf(mx, __shfl_xor(mx, 2, 64));
            mx = fmaxf(mx, __shfl_xor(mx, 4, 64));
            mx = fmaxf(mx, __shfl_xor(mx, 8, 64));
            float mn = fmaxf(m4[r], mx);
            al[r] = __expf(m4[r] - mn);
            m4[r] = mn;
            float p0 = __expf(s[0][r] - mn);
            float p1 = __expf(s[1][r] - mn);
            float p2 = __expf(s[2][r] - mn);
            float p3 = __expf(s[3][r] - mn);
            float rs = p0 + p1 + p2 + p3;
            rs += __shfl_xor(rs, 1, 64);
            rs += __shfl_xor(rs, 2, 64);
            rs += __shfl_xor(rs, 4, 64);
            rs += __shfl_xor(rs, 8, 64);
            l4[r] = l4[r] * al[r] + rs;
            Ps[w][(quad * 4 + r) * 72 +  0 + l15] = f2bf(p0);
            Ps[w][(quad * 4 + r) * 72 + 16 + l15] = f2bf(p1);
            Ps[w][(quad * 4 + r) * 72 + 32 + l15] = f2bf(p2);
            Ps[w][(quad * 4 + r) * 72 + 48 + l15] = f2bf(p3);
        }
        #pragma unroll
        for (int c = 0; c < 4; c++)
            #pragma unroll
            for (int r = 0; r < 4; r++) o[c][r] *= al[r];

        // O += P V
        #pragma unroll
        for (int kc = 0; kc < 2; kc++) {
            U8 pf;
            pf.u = *(const ushort8*)&Ps[w][l15 * 72 + kc * 32 + quad * 8];
            #pragma unroll
            for (int c = 0; c < 4; c++) {
                U8 vf;
                vf.u = *(const ushort8*)&Vt[(c * 16 + l15) * 72 + kc * 32 + quad * 8];
                o[c] = __builtin_amdgcn_mfma_f32_16x16x32_bf16(pf.b, vf.b, o[c], 0, 0, 0);
            }
        }
        __syncthreads();
    }

    // epilogue: normalize, write bf16 [16384][256]
    const int ds = bh >> 4, b = (bh >> 2) & 3, h = bh & 3;
    #pragma unroll
    for (int r = 0; r < 4; r++) {
        float inv = 1.f / l4[r];
        int q = q0 + w * 16 + quad * 4 + r;
        size_t row = (size_t)ds * NTOK + b * NN + q;
        #pragma unroll
        for (int c = 0; c < 4; c++)
            O[row * DD + h * HDIM + c * 16 + l15] = f2bf(o[c][r] * inv);
    }
}

// ---------------------------------------------------------------------------
// LayerNorm + exact GELU, f32 in-place, row width 512, one block per row.
// ---------------------------------------------------------------------------
__global__ __launch_bounds__(256) void ln_gelu(
    float* __restrict__ hb, const float* __restrict__ g,
    const float* __restrict__ be)
{
    __shared__ float r1[4], r2[4];
    const int t = threadIdx.x;
    const size_t row = blockIdx.x;
    float* ip = hb + row * 512;
    float x0 = ip[t], x1 = ip[t + 256];
    float s = x0 + x1, ss = x0 * x0 + x1 * x1;
    #pragma unroll
    for (int o = 32; o > 0; o >>= 1) { s += __shfl_down(s, o); ss += __shfl_down(ss, o); }
    if ((t & 63) == 0) { r1[t >> 6] = s; r2[t >> 6] = ss; }
    __syncthreads();
    float S  = r1[0] + r1[1] + r1[2] + r1[3];
    float SS = r2[0] + r2[1] + r2[2] + r2[3];
    float mean = S * (1.f / 512.f);
    float var  = SS * (1.f / 512.f) - mean * mean;
    float inv  = rsqrtf(var + 1e-5f);
    float y0 = (x0 - mean) * inv * g[t]       + be[t];
    float y1 = (x1 - mean) * inv * g[t + 256] + be[t + 256];
    ip[t]       = 0.5f * y0 * (1.f + erff(y0 * 0.70710678f));
    ip[t + 256] = 0.5f * y1 * (1.f + erff(y1 * 0.70710678f));
}

// ---------------------------------------------------------------------------
// cat[row][0:256] = src (f32 pair or bf16 stacked), bf16 out.
// ---------------------------------------------------------------------------
__global__ __launch_bounds__(256) void copy_to_cat(
    const float* s0, const float* s1, const unsigned short* sh,
    unsigned short* __restrict__ cat)
{
    int i = blockIdx.x * 256 + threadIdx.x;   // 4-elem groups over 16384*256
    int row = i >> 6, c4 = (i & 63) * 4;
    ushort4 p;
    if (sh) {
        p = *(const ushort4*)&sh[(size_t)row * 256 + c4];
    } else {
        const float* s = (row < 8192) ? s0 : s1;
        float4 a = *(const float4*)&s[(size_t)(row & 8191) * 256 + c4];
        p.x = f2bf(a.x); p.y = f2bf(a.y); p.z = f2bf(a.z); p.w = f2bf(a.w);
    }
    *(ushort4*)&cat[(size_t)row * 512 + c4] = p;
}

// ---------------------------------------------------------------------------
extern "C" void kernel_launch(void* const* d_in, const int* in_sizes, int n_in,
                              void* d_out, int out_size, void* d_ws, size_t ws_size,
                              hipStream_t stream)
{
    const float* desc0 = (const float*)d_in[0];
    const float* desc1 = (const float*)d_in[1];
    const float* enc0  = (const float*)d_in[2];
    const float* enc1  = (const float*)d_in[3];
    const float* Wqkv  = (const float*)d_in[4];  const float* bqkv  = (const float*)d_in[5];
    const float* Wo_s  = (const float*)d_in[6];  const float* bo_s  = (const float*)d_in[7];
    const float* W1_s  = (const float*)d_in[8];  const float* b1_s  = (const float*)d_in[9];
    const float* g_s   = (const float*)d_in[10]; const float* be_s  = (const float*)d_in[11];
    const float* W2_s  = (const float*)d_in[12]; const float* b2_s  = (const float*)d_in[13];
    const float* Wqk_c = (const float*)d_in[14]; const float* bqk_c = (const float*)d_in[15];
    const float* Wv_c  = (const float*)d_in[16]; const float* bv_c  = (const float*)d_in[17];
    const float* Wo_c  = (const float*)d_in[18]; const float* bo_c  = (const float*)d_in[19];
    const float* W1_c  = (const float*)d_in[20]; const float* b1_c  = (const float*)d_in[21];
    const float* g_c   = (const float*)d_in[22]; const float* be_c  = (const float*)d_in[23];
    const float* W2_c  = (const float*)d_in[24]; const float* b2_c  = (const float*)d_in[25];

    char* ws = (char*)d_ws;
    unsigned short* wt  = (unsigned short*)ws;                      // 1,245,184 elems
    unsigned short* qb  = (unsigned short*)(ws + 2490368);
    unsigned short* kb  = (unsigned short*)(ws + 10878976);
    unsigned short* vb  = (unsigned short*)(ws + 19267584);
    unsigned short* msg = (unsigned short*)(ws + 27656192);         // [16384][256]
    unsigned short* cat = (unsigned short*)(ws + 36044800);         // [16384][512]
    float*          hb  = (float*)        (ws + 52822016);          // [16384][512] f32
    unsigned short* dbf = (unsigned short*)(ws + 86376448);         // [16384][256]

    // transposed weight offsets within wt
    unsigned short* t_qkv = wt;
    unsigned short* t_wos = wt + 196608;
    unsigned short* t_w1s = wt + 262144;
    unsigned short* t_w2s = wt + 524288;
    unsigned short* t_wqk = wt + 655360;
    unsigned short* t_wv  = wt + 720896;
    unsigned short* t_woc = wt + 786432;
    unsigned short* t_w1c = wt + 851968;
    unsigned short* t_w2c = wt + 1114112;

    float* outF = (float*)d_out;   // [16384][256]

    dim3 blk(256);

    // ---- 1. weight transpose/convert ----
    WTab tab;
    tab.w[0] = Wqkv;  tab.o[0] = t_qkv; tab.K[0] = 256; tab.N[0] = 768;
    tab.w[1] = Wo_s;  tab.o[1] = t_wos; tab.K[1] = 256; tab.N[1] = 256;
    tab.w[2] = W1_s;  tab.o[2] = t_w1s; tab.K[2] = 512; tab.N[2] = 512;
    tab.w[3] = W2_s;  tab.o[3] = t_w2s; tab.K[3] = 512; tab.N[3] = 256;
    tab.w[4] = Wqk_c; tab.o[4] = t_wqk; tab.K[4] = 256; tab.N[4] = 256;
    tab.w[5] = Wv_c;  tab.o[5] = t_wv;  tab.K[5] = 256; tab.N[5] = 256;
    tab.w[6] = Wo_c;  tab.o[6] = t_woc; tab.K[6] = 256; tab.N[6] = 256;
    tab.w[7] = W1_c;  tab.o[7] = t_w1c; tab.K[7] = 512; tab.N[7] = 512;
    tab.w[8] = W2_c;  tab.o[8] = t_w2c; tab.K[8] = 512; tab.N[8] = 256;
    int acc_t = 0;
    for (int s = 0; s < 9; s++) {
        tab.t0[s] = acc_t;
        acc_t += (tab.K[s] / 32) * (tab.N[s] / 32);
    }
    tab.t0[9] = acc_t;   // 1216
    hipLaunchKernelGGL(wtrans, dim3(acc_t), blk, 0, stream, tab);

    auto gemm = [&](const void* A0, const void* A1, int lda, int a_f32,
                    const unsigned short* Wtp, int K, const float* bias, int Nc,
                    int mode, float* oF, unsigned short* oh0, unsigned short* oh1,
                    unsigned short* oh2, int ldc, const float* r0, const float* r1) {
        dim3 g(Nc / 64, NTOK2 / 128);
        hipLaunchKernelGGL(gemm_mfma, g, blk, 0, stream,
                           A0, A1, lda, a_f32, Wtp, K, bias, mode,
                           oF, oh0, oh1, oh2, ldc, r0, r1);
    };

    // ---- self block (both streams batched) ----
    gemm(desc0, desc1, 256, 1, t_qkv, 256, bqkv, 768, 3,
         nullptr, qb, kb, vb, 0, nullptr, nullptr);
    hipLaunchKernelGGL(rope_k, dim3(16384), blk, 0, stream, qb, kb, enc0, enc1);
    hipLaunchKernelGGL(flash_attn, dim3(NN / 64, 32), blk, 0, stream,
                       qb, kb, vb, msg, 0, 0.125f);
    hipLaunchKernelGGL(copy_to_cat, dim3(4096), blk, 0, stream,
                       desc0, desc1, (const unsigned short*)nullptr, cat);
    gemm(msg, msg + (size_t)NTOK * 256, 256, 0, t_wos, 256, bo_s, 256, 1,
         nullptr, cat + 256, nullptr, nullptr, 512, nullptr, nullptr);
    gemm(cat, cat + (size_t)NTOK * 512, 512, 0, t_w1s, 512, b1_s, 512, 0,
         hb, nullptr, nullptr, nullptr, 512, nullptr, nullptr);
    hipLaunchKernelGGL(ln_gelu, dim3(NTOK2), blk, 0, stream, hb, g_s, be_s);
    gemm(hb, hb + (size_t)NTOK * 512, 512, 1, t_w2s, 512, b2_s, 256, 4,
         outF, dbf, nullptr, nullptr, 256, desc0, desc1);

    // ---- cross block ----
    gemm(dbf, dbf + (size_t)NTOK * 256, 256, 0, t_wqk, 256, bqk_c, 256, 2,
         nullptr, qb, nullptr, nullptr, 0, nullptr, nullptr);
    gemm(dbf, dbf + (size_t)NTOK * 256, 256, 0, t_wv, 256, bv_c, 256, 2,
         nullptr, vb, nullptr, nullptr, 0, nullptr, nullptr);
    hipLaunchKernelGGL(flash_attn, dim3(NN / 64, 32), blk, 0, stream,
                       qb, qb, vb, msg, 16, 0.125f);
    hipLaunchKernelGGL(copy_to_cat, dim3(4096), blk, 0, stream,
                       nullptr, nullptr, dbf, cat);
    gemm(msg, msg + (size_t)NTOK * 256, 256, 0, t_woc, 256, bo_c, 256, 1,
         nullptr, cat + 256, nullptr, nullptr, 512, nullptr, nullptr);
    gemm(cat, cat + (size_t)NTOK * 512, 512, 0, t_w1c, 512, b1_c, 512, 0,
         hb, nullptr, nullptr, nullptr, 512, nullptr, nullptr);
    hipLaunchKernelGGL(ln_gelu, dim3(NTOK2), blk, 0, stream, hb, g_c, be_c);
    gemm(hb, hb + (size_t)NTOK * 512, 512, 1, t_w2c, 512, b2_c, 256, 4,
         outF, nullptr, nullptr, nullptr, 256, outF, outF + (size_t)NTOK * 256);
}

// Round 4
// 652.535 us; speedup vs baseline: 4.2872x; 1.0416x over previous
//
#include <hip/hip_runtime.h>
#include <math.h>

#define BB 4
#define HH 4
#define NN 2048
#define DD 256
#define HDIM 64
#define NTOK 8192
#define NTOK2 16384

typedef __attribute__((ext_vector_type(8))) __bf16 bf16x8;
typedef __attribute__((ext_vector_type(8))) unsigned short ushort8;
typedef __attribute__((ext_vector_type(4))) float floatx4;

union U8 { ushort8 u; bf16x8 b; };

__device__ __forceinline__ unsigned short f2bf(float x) {
    unsigned int u = __float_as_uint(x);
    u += 0x7FFF + ((u >> 16) & 1);
    return (unsigned short)(u >> 16);
}
__device__ __forceinline__ float bf2f(unsigned short u) {
    return __uint_as_float(((unsigned int)u) << 16);
}

#define GLD(gp, lp) __builtin_amdgcn_global_load_lds( \
    (const __attribute__((address_space(1))) void*)(gp), \
    (__attribute__((address_space(3))) void*)(lp), 16, 0, 0)

// ---------------------------------------------------------------------------
// Weight transpose+convert: W[K][N] f32 -> Wt[N][K] bf16.  One dispatch, 9 segs.
// ---------------------------------------------------------------------------
struct WTab {
    const float* w[9];
    unsigned short* o[9];
    int K[9];
    int N[9];
    int t0[10];
};

__global__ __launch_bounds__(256) void wtrans(WTab tab)
{
    __shared__ float lds[32][33];
    const int t = threadIdx.x;
    int bid = blockIdx.x;
    int s = 0;
    while (bid >= tab.t0[s + 1]) s++;
    const int ti = bid - tab.t0[s];
    const int K = tab.K[s], N = tab.N[s];
    const int tx = ti % (N / 32), ty = ti / (N / 32);
    const int k0 = ty * 32, n0 = tx * 32;
    const float* W = tab.w[s];
    unsigned short* Wt = tab.o[s];

    {
        int r = t >> 3, c = (t & 7) * 4;
        float4 a = *(const float4*)&W[(size_t)(k0 + r) * N + n0 + c];
        lds[r][c] = a.x; lds[r][c+1] = a.y; lds[r][c+2] = a.z; lds[r][c+3] = a.w;
    }
    __syncthreads();
    {
        int n = t >> 3, kq = (t & 7) * 4;
        ushort4 p;
        p.x = f2bf(lds[kq+0][n]); p.y = f2bf(lds[kq+1][n]);
        p.z = f2bf(lds[kq+2][n]); p.w = f2bf(lds[kq+3][n]);
        *(ushort4*)&Wt[(size_t)(n0 + n) * K + k0 + kq] = p;
    }
}

// ---------------------------------------------------------------------------
// bf16 MFMA GEMM, m97 structure: C[16384][N] = A @ Wt^T + bias.
// Tile 128x128, 4 waves (2x2), each wave 64x64 via 4x4 16x16x32 frags.
// Staging via global_load_lds(16B), unpadded 64B LDS rows.
// modes: 0 f32 row-major | 1 bf16 row-major | 2 bf16 head-scatter
//        3 bf16 qkv-scatter | 4 f32 = acc+bias+R (+ optional bf16 copies)
// ---------------------------------------------------------------------------
__global__ __launch_bounds__(256) void gemm_mfma(
    const unsigned short* __restrict__ A, int lda,
    const unsigned short* __restrict__ Wt, int K,
    const float* __restrict__ bias, int mode,
    float* outF, unsigned short* outH0, unsigned short* outH1,
    unsigned short* outH2,
    int ldc, const float* R0, const float* R1)
{
    __shared__ __align__(16) unsigned short As[128 * 32];
    __shared__ __align__(16) unsigned short Bs[128 * 32];
    const int t = threadIdx.x;
    const int w = t >> 6, lane = t & 63, quad = lane >> 4, l15 = lane & 15;
    const int m0 = blockIdx.y * 128, n0 = blockIdx.x * 128;
    const int wm = (w >> 1) * 64, wn = (w & 1) * 64;
    const int lr = lane >> 2, lc = (lane & 3) * 8;

    floatx4 acc[4][4];
    #pragma unroll
    for (int i = 0; i < 4; i++)
        #pragma unroll
        for (int j = 0; j < 4; j++) acc[i][j] = (floatx4){0.f, 0.f, 0.f, 0.f};

    for (int k0 = 0; k0 < K; k0 += 32) {
        // stage A(128x32) and B(128x32) bf16 via direct-to-LDS DMA
        GLD(A  + (size_t)(m0 + w * 32      + lr) * lda + k0 + lc, &As[(w * 32) * 32]);
        GLD(A  + (size_t)(m0 + w * 32 + 16 + lr) * lda + k0 + lc, &As[(w * 32 + 16) * 32]);
        GLD(Wt + (size_t)(n0 + w * 32      + lr) * K   + k0 + lc, &Bs[(w * 32) * 32]);
        GLD(Wt + (size_t)(n0 + w * 32 + 16 + lr) * K   + k0 + lc, &Bs[(w * 32 + 16) * 32]);
        __syncthreads();

        U8 af[4], bf[4];
        #pragma unroll
        for (int i = 0; i < 4; i++)
            af[i].u = *(const ushort8*)&As[(wm + i * 16 + l15) * 32 + quad * 8];
        #pragma unroll
        for (int j = 0; j < 4; j++)
            bf[j].u = *(const ushort8*)&Bs[(wn + j * 16 + l15) * 32 + quad * 8];
        #pragma unroll
        for (int i = 0; i < 4; i++)
            #pragma unroll
            for (int j = 0; j < 4; j++)
                acc[i][j] = __builtin_amdgcn_mfma_f32_16x16x32_bf16(af[i].b, bf[j].b, acc[i][j], 0, 0, 0);
        __syncthreads();
    }

    // epilogue
    #pragma unroll
    for (int i = 0; i < 4; i++) {
        #pragma unroll
        for (int j = 0; j < 4; j++) {
            int col = n0 + wn + j * 16 + l15;
            float bv = bias[col];
            #pragma unroll
            for (int r = 0; r < 4; r++) {
                int grow = m0 + wm + i * 16 + quad * 4 + r;
                float v = acc[i][j][r] + bv;
                if (mode == 0) {
                    outF[(size_t)grow * ldc + col] = v;
                } else if (mode == 1) {
                    outH0[(size_t)grow * ldc + col] = f2bf(v);
                } else if (mode == 2) {
                    int h = col >> 6, d = col & 63;
                    int ds = grow >> 13, b = (grow >> 11) & 3, n = grow & 2047;
                    int bh = ds * 16 + b * 4 + h;
                    outH0[((size_t)bh * NN + n) * HDIM + d] = f2bf(v);
                } else if (mode == 3) {
                    int sel = col % 3, cc = col / 3;
                    int h = cc >> 6, d = cc & 63;
                    int ds = grow >> 13, b = (grow >> 11) & 3, n = grow & 2047;
                    int bh = ds * 16 + b * 4 + h;
                    unsigned short* dst = (sel == 0) ? outH0 : ((sel == 1) ? outH1 : outH2);
                    dst[((size_t)bh * NN + n) * HDIM + d] = f2bf(v);
                } else {
                    const float* R = (grow < NTOK) ? R0 : R1;
                    float vv = v + R[(size_t)(grow & 8191) * 256 + col];
                    outF[(size_t)grow * 256 + col] = vv;
                    if (outH0) outH0[(size_t)grow * 256 + col] = f2bf(vv);
                    if (outH1) outH1[(size_t)grow * 512 + col] = f2bf(vv);
                }
            }
        }
    }
}

// ---------------------------------------------------------------------------
// RoPE in place on qb and kb (bf16 [32][2048][64]); enc0/enc1 f32 [2,B,1,N,HD].
// ---------------------------------------------------------------------------
__global__ __launch_bounds__(256) void rope_k(unsigned short* __restrict__ qb,
                                              unsigned short* __restrict__ kb,
                                              const float* __restrict__ enc0,
                                              const float* __restrict__ enc1)
{
    int i = blockIdx.x * 256 + threadIdx.x;     // 2^22 pair slots
    int dp = (i & 31) * 2;
    int n  = (i >> 5) & (NN - 1);
    int h  = (i >> 16) & 3;
    int b  = (i >> 18) & 3;
    int ds = (i >> 20) & 1;
    int bf = (i >> 21) & 1;
    unsigned short* tq = (bf ? kb : qb) +
        (((size_t)(ds * 16 + b * 4 + h)) * NN + n) * HDIM + dp;
    const float* e0 = (ds ? enc1 : enc0) + ((size_t)b * NN + n) * HDIM + dp;
    const float* e1 = e0 + (size_t)BB * NN * HDIM;
    float x0 = bf2f(tq[0]), x1 = bf2f(tq[1]);
    float y0 = x0 * e0[0] - x1 * e1[0];
    float y1 = x1 * e0[1] + x0 * e1[1];
    tq[0] = f2bf(y0); tq[1] = f2bf(y1);
}

// ---------------------------------------------------------------------------
// MFMA bf16 flash attention, bf16 in/out.  Q,K,V: [32][2048][64] bf16.
// KV head index = bh ^ kvx (kvx=0 self, 16 cross).  O: bf16 [16384][256].
// qscale includes log2(e); softmax in base-2 domain.
// ---------------------------------------------------------------------------
__global__ __launch_bounds__(256) void flash_attn(
    const unsigned short* __restrict__ Q, const unsigned short* __restrict__ K,
    const unsigned short* __restrict__ V, unsigned short* __restrict__ O,
    int kvx, float qscale)
{
    __shared__ __align__(16) unsigned short Ks[64 * 72];    // [key][hd]
    __shared__ __align__(16) unsigned short Vt[64 * 72];    // [hd][key]
    __shared__ __align__(16) unsigned short Ps[4][16 * 76]; // per-wave P [q][key], stride 76

    const int t    = threadIdx.x;
    const int w    = t >> 6;
    const int lane = t & 63;
    const int quad = lane >> 4;
    const int l15  = lane & 15;
    const int bh   = blockIdx.y;
    const int kbh  = bh ^ kvx;
    const int q0   = blockIdx.x * 64;

    const unsigned short* Qb = Q + (size_t)bh  * NN * HDIM;
    const unsigned short* Kb = K + (size_t)kbh * NN * HDIM;
    const unsigned short* Vb = V + (size_t)kbh * NN * HDIM;

    // Q fragments (A-layout), scale*log2e folded
    const int qrow = q0 + w * 16 + l15;
    bf16x8 qf0, qf1;
    {
        U8 r0, r1, x0, x1;
        r0.u = *(const ushort8*)&Qb[(size_t)qrow * HDIM + quad * 8];
        r1.u = *(const ushort8*)&Qb[(size_t)qrow * HDIM + 32 + quad * 8];
        #pragma unroll
        for (int j = 0; j < 8; j++) {
            x0.u[j] = f2bf(bf2f(r0.u[j]) * qscale);
            x1.u[j] = f2bf(bf2f(r1.u[j]) * qscale);
        }
        qf0 = x0.b; qf1 = x1.b;
    }

    floatx4 o[4];
    #pragma unroll
    for (int c = 0; c < 4; c++) o[c] = (floatx4){0.f, 0.f, 0.f, 0.f};
    float m4[4] = {-1e30f, -1e30f, -1e30f, -1e30f};
    float l4[4] = {0.f, 0.f, 0.f, 0.f};

    for (int j0 = 0; j0 < NN; j0 += 64) {
        // stage K rows (pure copy)
        #pragma unroll
        for (int f = t; f < 512; f += 256) {
            int r = f >> 3, ch = (f & 7) * 8;
            *(ushort8*)&Ks[r * 72 + ch] =
                *(const ushort8*)&Kb[(size_t)(j0 + r) * HDIM + ch];
        }
        // stage V transposed: paired-key b32 writes
        #pragma unroll
        for (int f = t; f < 512; f += 256) {
            int kp = f & 31, c4 = (f >> 5) * 4;
            ushort4 v0 = *(const ushort4*)&Vb[(size_t)(j0 + 2 * kp) * HDIM + c4];
            ushort4 v1 = *(const ushort4*)&Vb[(size_t)(j0 + 2 * kp + 1) * HDIM + c4];
            *(unsigned int*)&Vt[(c4 + 0) * 72 + 2 * kp] = (unsigned int)v0.x | ((unsigned int)v1.x << 16);
            *(unsigned int*)&Vt[(c4 + 1) * 72 + 2 * kp] = (unsigned int)v0.y | ((unsigned int)v1.y << 16);
            *(unsigned int*)&Vt[(c4 + 2) * 72 + 2 * kp] = (unsigned int)v0.z | ((unsigned int)v1.z << 16);
            *(unsigned int*)&Vt[(c4 + 3) * 72 + 2 * kp] = (unsigned int)v0.w | ((unsigned int)v1.w << 16);
        }
        __syncthreads();

        // S = (qscale*Q) K^T
        floatx4 s[4];
        #pragma unroll
        for (int t4 = 0; t4 < 4; t4++) {
            U8 k0, k1;
            k0.u = *(const ushort8*)&Ks[(t4 * 16 + l15) * 72 + quad * 8];
            k1.u = *(const ushort8*)&Ks[(t4 * 16 + l15) * 72 + 32 + quad * 8];
            floatx4 z = (floatx4){0.f, 0.f, 0.f, 0.f};
            z = __builtin_amdgcn_mfma_f32_16x16x32_bf16(qf0, k0.b, z, 0, 0, 0);
            z = __builtin_amdgcn_mfma_f32_16x16x32_bf16(qf1, k1.b, z, 0, 0, 0);
            s[t4] = z;
        }

        // online softmax (base-2)
        float al[4];
        #pragma unroll
        for (int r = 0; r < 4; r++) {
            float mx = fmaxf(fmaxf(s[0][r], s[1][r]), fmaxf(s[2][r], s[3][r]));
            mx = fmaxf(mx, __shfl_xor(mx, 1, 64));
            mx = fmaxf(mx, __shfl_xor(mx, 2, 64));
            mx = fmaxf(mx, __shfl_xor(mx, 4, 64));
            mx = fmaxf(mx, __shfl_xor(mx, 8, 64));
            float mn = fmaxf(m4[r], mx);
            al[r] = exp2f(m4[r] - mn);
            m4[r] = mn;
            float p0 = exp2f(s[0][r] - mn);
            float p1 = exp2f(s[1][r] - mn);
            float p2 = exp2f(s[2][r] - mn);
            float p3 = exp2f(s[3][r] - mn);
            float rs = p0 + p1 + p2 + p3;
            rs += __shfl_xor(rs, 1, 64);
            rs += __shfl_xor(rs, 2, 64);
            rs += __shfl_xor(rs, 4, 64);
            rs += __shfl_xor(rs, 8, 64);
            l4[r] = l4[r] * al[r] + rs;
            Ps[w][(quad * 4 + r) * 76 +  0 + l15] = f2bf(p0);
            Ps[w][(quad * 4 + r) * 76 + 16 + l15] = f2bf(p1);
            Ps[w][(quad * 4 + r) * 76 + 32 + l15] = f2bf(p2);
            Ps[w][(quad * 4 + r) * 76 + 48 + l15] = f2bf(p3);
        }
        #pragma unroll
        for (int c = 0; c < 4; c++)
            #pragma unroll
            for (int r = 0; r < 4; r++) o[c][r] *= al[r];

        // O += P V
        #pragma unroll
        for (int kc = 0; kc < 2; kc++) {
            U8 pf;
            pf.u = *(const ushort8*)&Ps[w][l15 * 76 + kc * 32 + quad * 8];
            #pragma unroll
            for (int c = 0; c < 4; c++) {
                U8 vf;
                vf.u = *(const ushort8*)&Vt[(c * 16 + l15) * 72 + kc * 32 + quad * 8];
                o[c] = __builtin_amdgcn_mfma_f32_16x16x32_bf16(pf.b, vf.b, o[c], 0, 0, 0);
            }
        }
        __syncthreads();
    }

    // epilogue: normalize, write bf16 [16384][256]
    const int ds = bh >> 4, b = (bh >> 2) & 3, h = bh & 3;
    #pragma unroll
    for (int r = 0; r < 4; r++) {
        float inv = 1.f / l4[r];
        int q = q0 + w * 16 + quad * 4 + r;
        size_t row = (size_t)ds * NTOK + b * NN + q;
        #pragma unroll
        for (int c = 0; c < 4; c++)
            O[row * DD + h * HDIM + c * 16 + l15] = f2bf(o[c][r] * inv);
    }
}

// ---------------------------------------------------------------------------
// LayerNorm + exact GELU: hb f32 in -> hbf bf16 out.  One block per 512-row.
// ---------------------------------------------------------------------------
__global__ __launch_bounds__(256) void ln_gelu(
    const float* __restrict__ hb, unsigned short* __restrict__ hbf,
    const float* __restrict__ g, const float* __restrict__ be)
{
    __shared__ float r1[4], r2[4];
    const int t = threadIdx.x;
    const size_t row = blockIdx.x;
    const float* ip = hb + row * 512;
    float x0 = ip[t], x1 = ip[t + 256];
    float s = x0 + x1, ss = x0 * x0 + x1 * x1;
    #pragma unroll
    for (int o = 32; o > 0; o >>= 1) { s += __shfl_down(s, o); ss += __shfl_down(ss, o); }
    if ((t & 63) == 0) { r1[t >> 6] = s; r2[t >> 6] = ss; }
    __syncthreads();
    float S  = r1[0] + r1[1] + r1[2] + r1[3];
    float SS = r2[0] + r2[1] + r2[2] + r2[3];
    float mean = S * (1.f / 512.f);
    float var  = SS * (1.f / 512.f) - mean * mean;
    float inv  = rsqrtf(var + 1e-5f);
    float y0 = (x0 - mean) * inv * g[t]       + be[t];
    float y1 = (x1 - mean) * inv * g[t + 256] + be[t + 256];
    unsigned short* op = hbf + row * 512;
    op[t]       = f2bf(0.5f * y0 * (1.f + erff(y0 * 0.70710678f)));
    op[t + 256] = f2bf(0.5f * y1 * (1.f + erff(y1 * 0.70710678f)));
}

// ---------------------------------------------------------------------------
// cat[row][0:256] = desc (f32 pair) as bf16.
// ---------------------------------------------------------------------------
__global__ __launch_bounds__(256) void copy_to_cat(
    const float* __restrict__ s0, const float* __restrict__ s1,
    unsigned short* __restrict__ cat)
{
    int i = blockIdx.x * 256 + threadIdx.x;   // 4-elem groups over 16384*256
    int row = i >> 6, c4 = (i & 63) * 4;
    const float* s = (row < NTOK) ? s0 : s1;
    float4 a = *(const float4*)&s[(size_t)(row & 8191) * 256 + c4];
    ushort4 p = { f2bf(a.x), f2bf(a.y), f2bf(a.z), f2bf(a.w) };
    *(ushort4*)&cat[(size_t)row * 512 + c4] = p;
}

// ---------------------------------------------------------------------------
extern "C" void kernel_launch(void* const* d_in, const int* in_sizes, int n_in,
                              void* d_out, int out_size, void* d_ws, size_t ws_size,
                              hipStream_t stream)
{
    const float* desc0 = (const float*)d_in[0];
    const float* desc1 = (const float*)d_in[1];
    const float* enc0  = (const float*)d_in[2];
    const float* enc1  = (const float*)d_in[3];
    const float* Wqkv  = (const float*)d_in[4];  const float* bqkv  = (const float*)d_in[5];
    const float* Wo_s  = (const float*)d_in[6];  const float* bo_s  = (const float*)d_in[7];
    const float* W1_s  = (const float*)d_in[8];  const float* b1_s  = (const float*)d_in[9];
    const float* g_s   = (const float*)d_in[10]; const float* be_s  = (const float*)d_in[11];
    const float* W2_s  = (const float*)d_in[12]; const float* b2_s  = (const float*)d_in[13];
    const float* Wqk_c = (const float*)d_in[14]; const float* bqk_c = (const float*)d_in[15];
    const float* Wv_c  = (const float*)d_in[16]; const float* bv_c  = (const float*)d_in[17];
    const float* Wo_c  = (const float*)d_in[18]; const float* bo_c  = (const float*)d_in[19];
    const float* W1_c  = (const float*)d_in[20]; const float* b1_c  = (const float*)d_in[21];
    const float* g_c   = (const float*)d_in[22]; const float* be_c  = (const float*)d_in[23];
    const float* W2_c  = (const float*)d_in[24]; const float* b2_c  = (const float*)d_in[25];

    char* ws = (char*)d_ws;
    unsigned short* wt  = (unsigned short*)ws;                      // 2,490,368 B
    unsigned short* qb  = (unsigned short*)(ws + 2490368);          // 8,388,608 B
    unsigned short* kb  = (unsigned short*)(ws + 10878976);         // 8,388,608 B
    unsigned short* msg = (unsigned short*)(ws + 19267584);         // 8,388,608 B
    unsigned short* hbf = (unsigned short*)(ws + 10878976);         // aliases kb+msg (16.8 MB)
    unsigned short* vb  = (unsigned short*)(ws + 27656192);         // 8,388,608 B
    unsigned short* cat = (unsigned short*)(ws + 36044800);         // 16,777,216 B
    float*          hb  = (float*)        (ws + 52822016);          // 33,554,432 B
    unsigned short* dbf = (unsigned short*)(ws + 86376448);         // 8,388,608 B -> 94.77 MB total

    // transposed weight offsets within wt
    unsigned short* t_qkv = wt;
    unsigned short* t_wos = wt + 196608;
    unsigned short* t_w1s = wt + 262144;
    unsigned short* t_w2s = wt + 524288;
    unsigned short* t_wqk = wt + 655360;
    unsigned short* t_wv  = wt + 720896;
    unsigned short* t_woc = wt + 786432;
    unsigned short* t_w1c = wt + 851968;
    unsigned short* t_w2c = wt + 1114112;

    float* outF = (float*)d_out;   // [16384][256]

    dim3 blk(256);

    // ---- weight transpose/convert ----
    WTab tab;
    tab.w[0] = Wqkv;  tab.o[0] = t_qkv; tab.K[0] = 256; tab.N[0] = 768;
    tab.w[1] = Wo_s;  tab.o[1] = t_wos; tab.K[1] = 256; tab.N[1] = 256;
    tab.w[2] = W1_s;  tab.o[2] = t_w1s; tab.K[2] = 512; tab.N[2] = 512;
    tab.w[3] = W2_s;  tab.o[3] = t_w2s; tab.K[3] = 512; tab.N[3] = 256;
    tab.w[4] = Wqk_c; tab.o[4] = t_wqk; tab.K[4] = 256; tab.N[4] = 256;
    tab.w[5] = Wv_c;  tab.o[5] = t_wv;  tab.K[5] = 256; tab.N[5] = 256;
    tab.w[6] = Wo_c;  tab.o[6] = t_woc; tab.K[6] = 256; tab.N[6] = 256;
    tab.w[7] = W1_c;  tab.o[7] = t_w1c; tab.K[7] = 512; tab.N[7] = 512;
    tab.w[8] = W2_c;  tab.o[8] = t_w2c; tab.K[8] = 512; tab.N[8] = 256;
    int acc_t = 0;
    for (int s = 0; s < 9; s++) {
        tab.t0[s] = acc_t;
        acc_t += (tab.K[s] / 32) * (tab.N[s] / 32);
    }
    tab.t0[9] = acc_t;
    hipLaunchKernelGGL(wtrans, dim3(acc_t), blk, 0, stream, tab);

    auto gemm = [&](const unsigned short* A, int lda, const unsigned short* Wtp,
                    int K, const float* bias, int Nc, int mode,
                    float* oF, unsigned short* oh0, unsigned short* oh1,
                    unsigned short* oh2, int ldc, const float* r0, const float* r1) {
        dim3 g(Nc / 128, NTOK2 / 128);
        hipLaunchKernelGGL(gemm_mfma, g, blk, 0, stream,
                           A, lda, Wtp, K, bias, mode, oF, oh0, oh1, oh2, ldc, r0, r1);
    };

    const float QS = 0.125f * 1.44269504088896f;

    // ---- self block (both streams batched) ----
    hipLaunchKernelGGL(copy_to_cat, dim3(4096), blk, 0, stream, desc0, desc1, cat);
    gemm(cat, 512, t_qkv, 256, bqkv, 768, 3,
         nullptr, qb, kb, vb, 0, nullptr, nullptr);
    hipLaunchKernelGGL(rope_k, dim3(16384), blk, 0, stream, qb, kb, enc0, enc1);
    hipLaunchKernelGGL(flash_attn, dim3(NN / 64, 32), blk, 0, stream,
                       qb, kb, vb, msg, 0, QS);
    gemm(msg, 256, t_wos, 256, bo_s, 256, 1,
         nullptr, cat + 256, nullptr, nullptr, 512, nullptr, nullptr);
    gemm(cat, 512, t_w1s, 512, b1_s, 512, 0,
         hb, nullptr, nullptr, nullptr, 512, nullptr, nullptr);
    hipLaunchKernelGGL(ln_gelu, dim3(NTOK2), blk, 0, stream, hb, hbf, g_s, be_s);
    gemm(hbf, 512, t_w2s, 512, b2_s, 256, 4,
         outF, dbf, cat, nullptr, 256, desc0, desc1);

    // ---- cross block ----
    gemm(dbf, 256, t_wqk, 256, bqk_c, 256, 2,
         nullptr, qb, nullptr, nullptr, 0, nullptr, nullptr);
    gemm(dbf, 256, t_wv, 256, bv_c, 256, 2,
         nullptr, vb, nullptr, nullptr, 0, nullptr, nullptr);
    hipLaunchKernelGGL(flash_attn, dim3(NN / 64, 32), blk, 0, stream,
                       qb, qb, vb, msg, 16, QS);
    gemm(msg, 256, t_woc, 256, bo_c, 256, 1,
         nullptr, cat + 256, nullptr, nullptr, 512, nullptr, nullptr);
    gemm(cat, 512, t_w1c, 512, b1_c, 512, 0,
         hb, nullptr, nullptr, nullptr, 512, nullptr, nullptr);
    hipLaunchKernelGGL(ln_gelu, dim3(NTOK2), blk, 0, stream, hb, hbf, g_c, be_c);
    gemm(hbf, 512, t_w2c, 512, b2_c, 256, 4,
         outF, nullptr, nullptr, nullptr, 256, outF, outF + (size_t)NTOK * 256);
}

// Round 6
// 557.209 us; speedup vs baseline: 5.0206x; 1.1711x over previous
//
#include <hip/hip_runtime.h>
#include <math.h>

#define BB 4
#define HH 4
#define NN 2048
#define DD 256
#define HDIM 64
#define NTOK 8192
#define NTOK2 16384

typedef __attribute__((ext_vector_type(8))) __bf16 bf16x8;
typedef __attribute__((ext_vector_type(8))) unsigned short ushort8;
typedef __attribute__((ext_vector_type(4))) float floatx4;
typedef __attribute__((ext_vector_type(4))) short short4v;

union U8 { ushort8 u; bf16x8 b; };
union U4 { unsigned int u[2]; unsigned long long l; short4v s; };

// v_mfma_f32_16x16x16_bf16 (K=16): A/B = 4 bf16 per lane (short4), C/D = 4 f32.
// NOTE: do NOT guard with __has_builtin — it returns false for aux-target
// builtins in the HIP host pass while the builtin itself is accepted.
#define MFMA16(a, b, c) __builtin_amdgcn_mfma_f32_16x16x16bf16_1k(a, b, c, 0, 0, 0)

__device__ __forceinline__ unsigned short f2bf(float x) {
    unsigned int u = __float_as_uint(x);
    u += 0x7FFF + ((u >> 16) & 1);
    return (unsigned short)(u >> 16);
}
__device__ __forceinline__ float bf2f(unsigned short u) {
    return __uint_as_float(((unsigned int)u) << 16);
}
// round-half-up bf16 pair pack (a -> low16, b -> high16); inputs >= 0
__device__ __forceinline__ unsigned int pkbf(float a, float b) {
    return ((__float_as_uint(a) + 0x8000u) >> 16) |
           ((__float_as_uint(b) + 0x8000u) & 0xFFFF0000u);
}

#define GLD(gp, lp) __builtin_amdgcn_global_load_lds( \
    (const __attribute__((address_space(1))) void*)(gp), \
    (__attribute__((address_space(3))) void*)(lp), 16, 0, 0)

// ---------------------------------------------------------------------------
// Weight transpose+convert: W[K][N] f32 -> Wt[N][K] bf16.  One dispatch, 9 segs.
// ---------------------------------------------------------------------------
struct WTab {
    const float* w[9];
    unsigned short* o[9];
    int K[9];
    int N[9];
    int t0[10];
};

__global__ __launch_bounds__(256) void wtrans(WTab tab)
{
    __shared__ float lds[32][33];
    const int t = threadIdx.x;
    int bid = blockIdx.x;
    int s = 0;
    while (bid >= tab.t0[s + 1]) s++;
    const int ti = bid - tab.t0[s];
    const int K = tab.K[s], N = tab.N[s];
    const int tx = ti % (N / 32), ty = ti / (N / 32);
    const int k0 = ty * 32, n0 = tx * 32;
    const float* W = tab.w[s];
    unsigned short* Wt = tab.o[s];

    {
        int r = t >> 3, c = (t & 7) * 4;
        float4 a = *(const float4*)&W[(size_t)(k0 + r) * N + n0 + c];
        lds[r][c] = a.x; lds[r][c+1] = a.y; lds[r][c+2] = a.z; lds[r][c+3] = a.w;
    }
    __syncthreads();
    {
        int n = t >> 3, kq = (t & 7) * 4;
        ushort4 p;
        p.x = f2bf(lds[kq+0][n]); p.y = f2bf(lds[kq+1][n]);
        p.z = f2bf(lds[kq+2][n]); p.w = f2bf(lds[kq+3][n]);
        *(ushort4*)&Wt[(size_t)(n0 + n) * K + k0 + kq] = p;
    }
}

// ---------------------------------------------------------------------------
// bf16 MFMA GEMM, 128x128 tile, global_load_lds staging.
// modes: 1 bf16 row-major | 2 bf16 dual head-scatter (col<256 -> outH0 w/ bias,
//        col>=256 -> outH1 w/ bias2) | 3 bf16 qkv-scatter | 4 f32 residual out
// ---------------------------------------------------------------------------
__global__ __launch_bounds__(256) void gemm_mfma(
    const unsigned short* __restrict__ A, int lda,
    const unsigned short* __restrict__ Wt, int K,
    const float* __restrict__ bias, const float* __restrict__ bias2, int mode,
    float* outF, unsigned short* outH0, unsigned short* outH1,
    unsigned short* outH2,
    int ldc, const float* R0, const float* R1)
{
    __shared__ __align__(16) unsigned short As[128 * 32];
    __shared__ __align__(16) unsigned short Bs[128 * 32];
    const int t = threadIdx.x;
    const int w = t >> 6, lane = t & 63, quad = lane >> 4, l15 = lane & 15;
    const int m0 = blockIdx.y * 128, n0 = blockIdx.x * 128;
    const int wm = (w >> 1) * 64, wn = (w & 1) * 64;
    const int lr = lane >> 2, lc = (lane & 3) * 8;

    floatx4 acc[4][4];
    #pragma unroll
    for (int i = 0; i < 4; i++)
        #pragma unroll
        for (int j = 0; j < 4; j++) acc[i][j] = (floatx4){0.f, 0.f, 0.f, 0.f};

    for (int k0 = 0; k0 < K; k0 += 32) {
        GLD(A  + (size_t)(m0 + w * 32      + lr) * lda + k0 + lc, &As[(w * 32) * 32]);
        GLD(A  + (size_t)(m0 + w * 32 + 16 + lr) * lda + k0 + lc, &As[(w * 32 + 16) * 32]);
        GLD(Wt + (size_t)(n0 + w * 32      + lr) * K   + k0 + lc, &Bs[(w * 32) * 32]);
        GLD(Wt + (size_t)(n0 + w * 32 + 16 + lr) * K   + k0 + lc, &Bs[(w * 32 + 16) * 32]);
        __syncthreads();

        U8 af[4], bf[4];
        #pragma unroll
        for (int i = 0; i < 4; i++)
            af[i].u = *(const ushort8*)&As[(wm + i * 16 + l15) * 32 + quad * 8];
        #pragma unroll
        for (int j = 0; j < 4; j++)
            bf[j].u = *(const ushort8*)&Bs[(wn + j * 16 + l15) * 32 + quad * 8];
        #pragma unroll
        for (int i = 0; i < 4; i++)
            #pragma unroll
            for (int j = 0; j < 4; j++)
                acc[i][j] = __builtin_amdgcn_mfma_f32_16x16x32_bf16(af[i].b, bf[j].b, acc[i][j], 0, 0, 0);
        __syncthreads();
    }

    #pragma unroll
    for (int i = 0; i < 4; i++) {
        #pragma unroll
        for (int j = 0; j < 4; j++) {
            int col = n0 + wn + j * 16 + l15;
            float bv = (mode == 2 && col >= 256) ? bias2[col & 255] : bias[col];
            #pragma unroll
            for (int r = 0; r < 4; r++) {
                int grow = m0 + wm + i * 16 + quad * 4 + r;
                float v = acc[i][j][r] + bv;
                if (mode == 1) {
                    outH0[(size_t)grow * ldc + col] = f2bf(v);
                } else if (mode == 2) {
                    int cc = col & 255;
                    int h = cc >> 6, d = cc & 63;
                    int ds = grow >> 13, b = (grow >> 11) & 3, n = grow & 2047;
                    int bh = ds * 16 + b * 4 + h;
                    unsigned short* dst = (col < 256) ? outH0 : outH1;
                    dst[((size_t)bh * NN + n) * HDIM + d] = f2bf(v);
                } else if (mode == 3) {
                    int sel = col % 3, cc = col / 3;
                    int h = cc >> 6, d = cc & 63;
                    int ds = grow >> 13, b = (grow >> 11) & 3, n = grow & 2047;
                    int bh = ds * 16 + b * 4 + h;
                    unsigned short* dst = (sel == 0) ? outH0 : ((sel == 1) ? outH1 : outH2);
                    dst[((size_t)bh * NN + n) * HDIM + d] = f2bf(v);
                } else {
                    const float* R = (grow < NTOK) ? R0 : R1;
                    float vv = v + R[(size_t)(grow & 8191) * 256 + col];
                    outF[(size_t)grow * 256 + col] = vv;
                    if (outH0) outH0[(size_t)grow * 256 + col] = f2bf(vv);
                    if (outH1) outH1[(size_t)grow * 512 + col] = f2bf(vv);
                }
            }
        }
    }
}

// ---------------------------------------------------------------------------
// RoPE in place on qb and kb (bf16 [32][2048][64]); enc0/enc1 f32 [2,B,1,N,HD].
// ---------------------------------------------------------------------------
__global__ __launch_bounds__(256) void rope_k(unsigned short* __restrict__ qb,
                                              unsigned short* __restrict__ kb,
                                              const float* __restrict__ enc0,
                                              const float* __restrict__ enc1)
{
    int i = blockIdx.x * 256 + threadIdx.x;     // 2^22 pair slots
    int dp = (i & 31) * 2;
    int n  = (i >> 5) & (NN - 1);
    int h  = (i >> 16) & 3;
    int b  = (i >> 18) & 3;
    int ds = (i >> 20) & 1;
    int bf = (i >> 21) & 1;
    unsigned short* tq = (bf ? kb : qb) +
        (((size_t)(ds * 16 + b * 4 + h)) * NN + n) * HDIM + dp;
    const float* e0 = (ds ? enc1 : enc0) + ((size_t)b * NN + n) * HDIM + dp;
    const float* e1 = e0 + (size_t)BB * NN * HDIM;
    float x0 = bf2f(tq[0]), x1 = bf2f(tq[1]);
    float y0 = x0 * e0[0] - x1 * e1[0];
    float y1 = x1 * e0[1] + x0 * e1[1];
    tq[0] = f2bf(y0); tq[1] = f2bf(y1);
}

// ---------------------------------------------------------------------------
// MFMA bf16 flash attention, S^T formulation (K·Q^T): per-lane softmax state,
// in-register P -> PV via 16x16x16 MFMAs, no P LDS round-trip.
// Q,K,V: [32][2048][64] bf16; KV head = bh ^ kvx; O: bf16 [16384][256].
// qscale includes log2(e); softmax in base-2 domain.
// ---------------------------------------------------------------------------
__global__ __launch_bounds__(256) void flash_attn(
    const unsigned short* __restrict__ Q, const unsigned short* __restrict__ K,
    const unsigned short* __restrict__ V, unsigned short* __restrict__ O,
    int kvx, float qscale)
{
    __shared__ __align__(16) unsigned short Ks[64 * 72];    // [key][hd]
    __shared__ __align__(16) unsigned short Vt[64 * 72];    // [hd][key]

    const int t    = threadIdx.x;
    const int w    = t >> 6;
    const int lane = t & 63;
    const int quad = lane >> 4;
    const int l15  = lane & 15;
    const int bh   = blockIdx.y;
    const int kbh  = bh ^ kvx;
    const int q0   = blockIdx.x * 64;

    const unsigned short* Qb = Q + (size_t)bh  * NN * HDIM;
    const unsigned short* Kb = K + (size_t)kbh * NN * HDIM;
    const unsigned short* Vb = V + (size_t)kbh * NN * HDIM;

    // Q fragments: lane l15 = q-row, k(hd) = quad*8+j  (B-operand of K·Q^T)
    const int qrow = q0 + w * 16 + l15;
    bf16x8 qf0, qf1;
    {
        U8 r0, r1, x0, x1;
        r0.u = *(const ushort8*)&Qb[(size_t)qrow * HDIM + quad * 8];
        r1.u = *(const ushort8*)&Qb[(size_t)qrow * HDIM + 32 + quad * 8];
        #pragma unroll
        for (int j = 0; j < 8; j++) {
            x0.u[j] = f2bf(bf2f(r0.u[j]) * qscale);
            x1.u[j] = f2bf(bf2f(r1.u[j]) * qscale);
        }
        qf0 = x0.b; qf1 = x1.b;
    }

    floatx4 o[4];   // O^T accumulator: col = q = l15, row(hd) = c*16 + quad*4 + r
    #pragma unroll
    for (int c = 0; c < 4; c++) o[c] = (floatx4){0.f, 0.f, 0.f, 0.f};
    float m = -1e30f, l = 0.f;

    for (int j0 = 0; j0 < NN; j0 += 64) {
        // stage K rows (pure copy)
        #pragma unroll
        for (int f = t; f < 512; f += 256) {
            int r = f >> 3, ch = (f & 7) * 8;
            *(ushort8*)&Ks[r * 72 + ch] =
                *(const ushort8*)&Kb[(size_t)(j0 + r) * HDIM + ch];
        }
        // stage V transposed: paired-key b32 writes
        #pragma unroll
        for (int f = t; f < 512; f += 256) {
            int kp = f & 31, c4 = (f >> 5) * 4;
            ushort4 v0 = *(const ushort4*)&Vb[(size_t)(j0 + 2 * kp) * HDIM + c4];
            ushort4 v1 = *(const ushort4*)&Vb[(size_t)(j0 + 2 * kp + 1) * HDIM + c4];
            *(unsigned int*)&Vt[(c4 + 0) * 72 + 2 * kp] = (unsigned int)v0.x | ((unsigned int)v1.x << 16);
            *(unsigned int*)&Vt[(c4 + 1) * 72 + 2 * kp] = (unsigned int)v0.y | ((unsigned int)v1.y << 16);
            *(unsigned int*)&Vt[(c4 + 2) * 72 + 2 * kp] = (unsigned int)v0.z | ((unsigned int)v1.z << 16);
            *(unsigned int*)&Vt[(c4 + 3) * 72 + 2 * kp] = (unsigned int)v0.w | ((unsigned int)v1.w << 16);
        }
        __syncthreads();

        // S^T = K (qscale*Q)^T : A = K-tile rows, B = Q frags.
        // s[t4]: col = q = l15, row(key-in-tile) = quad*4 + r
        floatx4 s[4];
        #pragma unroll
        for (int t4 = 0; t4 < 4; t4++) {
            U8 k0, k1;
            k0.u = *(const ushort8*)&Ks[(t4 * 16 + l15) * 72 + quad * 8];
            k1.u = *(const ushort8*)&Ks[(t4 * 16 + l15) * 72 + 32 + quad * 8];
            floatx4 z = (floatx4){0.f, 0.f, 0.f, 0.f};
            z = __builtin_amdgcn_mfma_f32_16x16x32_bf16(k0.b, qf0, z, 0, 0, 0);
            z = __builtin_amdgcn_mfma_f32_16x16x32_bf16(k1.b, qf1, z, 0, 0, 0);
            s[t4] = z;
        }

        // per-lane online softmax (one q-row per lane; keys split across quads)
        float mx = s[0][0];
        #pragma unroll
        for (int t4 = 0; t4 < 4; t4++)
            #pragma unroll
            for (int r = 0; r < 4; r++) mx = fmaxf(mx, s[t4][r]);
        mx = fmaxf(mx, __shfl_xor(mx, 16, 64));
        mx = fmaxf(mx, __shfl_xor(mx, 32, 64));
        float mn = fmaxf(m, mx);
        float al = exp2f(m - mn);
        m = mn;
        float rs = 0.f;
        #pragma unroll
        for (int t4 = 0; t4 < 4; t4++)
            #pragma unroll
            for (int r = 0; r < 4; r++) {
                float p = exp2f(s[t4][r] - mn);
                s[t4][r] = p;
                rs += p;
            }
        rs += __shfl_xor(rs, 16, 64);
        rs += __shfl_xor(rs, 32, 64);
        l = l * al + rs;
        #pragma unroll
        for (int c = 0; c < 4; c++)
            #pragma unroll
            for (int r = 0; r < 4; r++) o[c][r] *= al;

        // pack P^T fragments: C/D layout of S^T == B-operand of 16x16x16
        short4v pf[4];
        #pragma unroll
        for (int t4 = 0; t4 < 4; t4++) {
            U4 pk;
            pk.u[0] = pkbf(s[t4][0], s[t4][1]);
            pk.u[1] = pkbf(s[t4][2], s[t4][3]);
            pf[t4] = pk.s;
        }

        // O^T += V^T P^T : A = V^T chunk [hd=c*16+l15][key=t4*16+quad*4+j]
        #pragma unroll
        for (int c = 0; c < 4; c++) {
            #pragma unroll
            for (int t4 = 0; t4 < 4; t4++) {
                U4 vf;
                vf.l = *(const unsigned long long*)
                    &Vt[(c * 16 + l15) * 72 + t4 * 16 + quad * 4];
                o[c] = MFMA16(vf.s, pf[t4], o[c]);
            }
        }
        __syncthreads();
    }

    // epilogue: normalize, write bf16 [16384][256]; lane owns q=l15, 16 hd vals
    const int ds = bh >> 4, b = (bh >> 2) & 3, h = bh & 3;
    const int q = q0 + w * 16 + l15;
    const size_t row = (size_t)ds * NTOK + b * NN + q;
    float inv = 1.f / l;
    #pragma unroll
    for (int c = 0; c < 4; c++) {
        ushort4 pk;
        pk.x = f2bf(o[c][0] * inv);
        pk.y = f2bf(o[c][1] * inv);
        pk.z = f2bf(o[c][2] * inv);
        pk.w = f2bf(o[c][3] * inv);
        *(ushort4*)&O[row * DD + h * HDIM + c * 16 + quad * 4] = pk;
    }
}

// ---------------------------------------------------------------------------
// LayerNorm + exact GELU, bf16 in-place, row width 512, one block per row.
// ---------------------------------------------------------------------------
__global__ __launch_bounds__(256) void ln_gelu(
    unsigned short* __restrict__ hb, const float* __restrict__ g,
    const float* __restrict__ be)
{
    __shared__ float r1[4], r2[4];
    const int t = threadIdx.x;
    const size_t row = blockIdx.x;
    unsigned short* ip = hb + row * 512;
    float x0 = bf2f(ip[t]), x1 = bf2f(ip[t + 256]);
    float s = x0 + x1, ss = x0 * x0 + x1 * x1;
    #pragma unroll
    for (int o = 32; o > 0; o >>= 1) { s += __shfl_down(s, o); ss += __shfl_down(ss, o); }
    if ((t & 63) == 0) { r1[t >> 6] = s; r2[t >> 6] = ss; }
    __syncthreads();
    float S  = r1[0] + r1[1] + r1[2] + r1[3];
    float SS = r2[0] + r2[1] + r2[2] + r2[3];
    float mean = S * (1.f / 512.f);
    float var  = SS * (1.f / 512.f) - mean * mean;
    float inv  = rsqrtf(var + 1e-5f);
    float y0 = (x0 - mean) * inv * g[t]       + be[t];
    float y1 = (x1 - mean) * inv * g[t + 256] + be[t + 256];
    ip[t]       = f2bf(0.5f * y0 * (1.f + erff(y0 * 0.70710678f)));
    ip[t + 256] = f2bf(0.5f * y1 * (1.f + erff(y1 * 0.70710678f)));
}

// ---------------------------------------------------------------------------
// cat[row][0:256] = desc (f32 pair) as bf16.
// ---------------------------------------------------------------------------
__global__ __launch_bounds__(256) void copy_to_cat(
    const float* __restrict__ s0, const float* __restrict__ s1,
    unsigned short* __restrict__ cat)
{
    int i = blockIdx.x * 256 + threadIdx.x;
    int row = i >> 6, c4 = (i & 63) * 4;
    const float* s = (row < NTOK) ? s0 : s1;
    float4 a = *(const float4*)&s[(size_t)(row & 8191) * 256 + c4];
    ushort4 p = { f2bf(a.x), f2bf(a.y), f2bf(a.z), f2bf(a.w) };
    *(ushort4*)&cat[(size_t)row * 512 + c4] = p;
}

// ---------------------------------------------------------------------------
extern "C" void kernel_launch(void* const* d_in, const int* in_sizes, int n_in,
                              void* d_out, int out_size, void* d_ws, size_t ws_size,
                              hipStream_t stream)
{
    const float* desc0 = (const float*)d_in[0];
    const float* desc1 = (const float*)d_in[1];
    const float* enc0  = (const float*)d_in[2];
    const float* enc1  = (const float*)d_in[3];
    const float* Wqkv  = (const float*)d_in[4];  const float* bqkv  = (const float*)d_in[5];
    const float* Wo_s  = (const float*)d_in[6];  const float* bo_s  = (const float*)d_in[7];
    const float* W1_s  = (const float*)d_in[8];  const float* b1_s  = (const float*)d_in[9];
    const float* g_s   = (const float*)d_in[10]; const float* be_s  = (const float*)d_in[11];
    const float* W2_s  = (const float*)d_in[12]; const float* b2_s  = (const float*)d_in[13];
    const float* Wqk_c = (const float*)d_in[14]; const float* bqk_c = (const float*)d_in[15];
    const float* Wv_c  = (const float*)d_in[16]; const float* bv_c  = (const float*)d_in[17];
    const float* Wo_c  = (const float*)d_in[18]; const float* bo_c  = (const float*)d_in[19];
    const float* W1_c  = (const float*)d_in[20]; const float* b1_c  = (const float*)d_in[21];
    const float* g_c   = (const float*)d_in[22]; const float* be_c  = (const float*)d_in[23];
    const float* W2_c  = (const float*)d_in[24]; const float* b2_c  = (const float*)d_in[25];

    char* ws = (char*)d_ws;
    unsigned short* wt  = (unsigned short*)ws;                      // 2,490,368 B
    unsigned short* qb  = (unsigned short*)(ws + 2490368);
    unsigned short* kb  = (unsigned short*)(ws + 10878976);
    unsigned short* msg = (unsigned short*)(ws + 19267584);
    unsigned short* vb  = (unsigned short*)(ws + 27656192);
    unsigned short* cat = (unsigned short*)(ws + 36044800);         // 16.8 MB
    unsigned short* hb  = (unsigned short*)(ws + 52822016);         // bf16 [16384][512]
    unsigned short* dbf = (unsigned short*)(ws + 86376448);

    // transposed weight offsets within wt (shorts); wqk rows 0-255 + wv rows
    // 256-511 are contiguous -> fused [512][256] for the cross qk+v GEMM
    unsigned short* t_qkv = wt;
    unsigned short* t_wos = wt + 196608;
    unsigned short* t_w1s = wt + 262144;
    unsigned short* t_w2s = wt + 524288;
    unsigned short* t_wqk = wt + 655360;
    unsigned short* t_wv  = wt + 720896;
    unsigned short* t_woc = wt + 786432;
    unsigned short* t_w1c = wt + 851968;
    unsigned short* t_w2c = wt + 1114112;

    float* outF = (float*)d_out;   // [16384][256]

    dim3 blk(256);

    WTab tab;
    tab.w[0] = Wqkv;  tab.o[0] = t_qkv; tab.K[0] = 256; tab.N[0] = 768;
    tab.w[1] = Wo_s;  tab.o[1] = t_wos; tab.K[1] = 256; tab.N[1] = 256;
    tab.w[2] = W1_s;  tab.o[2] = t_w1s; tab.K[2] = 512; tab.N[2] = 512;
    tab.w[3] = W2_s;  tab.o[3] = t_w2s; tab.K[3] = 512; tab.N[3] = 256;
    tab.w[4] = Wqk_c; tab.o[4] = t_wqk; tab.K[4] = 256; tab.N[4] = 256;
    tab.w[5] = Wv_c;  tab.o[5] = t_wv;  tab.K[5] = 256; tab.N[5] = 256;
    tab.w[6] = Wo_c;  tab.o[6] = t_woc; tab.K[6] = 256; tab.N[6] = 256;
    tab.w[7] = W1_c;  tab.o[7] = t_w1c; tab.K[7] = 512; tab.N[7] = 512;
    tab.w[8] = W2_c;  tab.o[8] = t_w2c; tab.K[8] = 512; tab.N[8] = 256;
    int acc_t = 0;
    for (int s = 0; s < 9; s++) {
        tab.t0[s] = acc_t;
        acc_t += (tab.K[s] / 32) * (tab.N[s] / 32);
    }
    tab.t0[9] = acc_t;
    hipLaunchKernelGGL(wtrans, dim3(acc_t), blk, 0, stream, tab);

    auto gemm = [&](const unsigned short* A, int lda, const unsigned short* Wtp,
                    int K, const float* bias, const float* bias2, int Nc, int mode,
                    float* oF, unsigned short* oh0, unsigned short* oh1,
                    unsigned short* oh2, int ldc, const float* r0, const float* r1) {
        dim3 g(Nc / 128, NTOK2 / 128);
        hipLaunchKernelGGL(gemm_mfma, g, blk, 0, stream,
                           A, lda, Wtp, K, bias, bias2, mode,
                           oF, oh0, oh1, oh2, ldc, r0, r1);
    };

    const float QS = 0.125f * 1.44269504088896f;

    // ---- self block (both streams batched) ----
    hipLaunchKernelGGL(copy_to_cat, dim3(4096), blk, 0, stream, desc0, desc1, cat);
    gemm(cat, 512, t_qkv, 256, bqkv, nullptr, 768, 3,
         nullptr, qb, kb, vb, 0, nullptr, nullptr);
    hipLaunchKernelGGL(rope_k, dim3(16384), blk, 0, stream, qb, kb, enc0, enc1);
    hipLaunchKernelGGL(flash_attn, dim3(NN / 64, 32), blk, 0, stream,
                       qb, kb, vb, msg, 0, QS);
    gemm(msg, 256, t_wos, 256, bo_s, nullptr, 256, 1,
         nullptr, cat + 256, nullptr, nullptr, 512, nullptr, nullptr);
    gemm(cat, 512, t_w1s, 512, b1_s, nullptr, 512, 1,
         nullptr, hb, nullptr, nullptr, 512, nullptr, nullptr);
    hipLaunchKernelGGL(ln_gelu, dim3(NTOK2), blk, 0, stream, hb, g_s, be_s);
    gemm(hb, 512, t_w2s, 512, b2_s, nullptr, 256, 4,
         outF, dbf, cat, nullptr, 256, desc0, desc1);

    // ---- cross block ----
    gemm(dbf, 256, t_wqk, 256, bqk_c, bv_c, 512, 2,
         nullptr, qb, vb, nullptr, 0, nullptr, nullptr);
    hipLaunchKernelGGL(flash_attn, dim3(NN / 64, 32), blk, 0, stream,
                       qb, qb, vb, msg, 16, QS);
    gemm(msg, 256, t_woc, 256, bo_c, nullptr, 256, 1,
         nullptr, cat + 256, nullptr, nullptr, 512, nullptr, nullptr);
    gemm(cat, 512, t_w1c, 512, b1_c, nullptr, 512, 1,
         nullptr, hb, nullptr, nullptr, 512, nullptr, nullptr);
    hipLaunchKernelGGL(ln_gelu, dim3(NTOK2), blk, 0, stream, hb, g_c, be_c);
    gemm(hb, 512, t_w2c, 512, b2_c, nullptr, 256, 4,
         outF, nullptr, nullptr, nullptr, 256, outF, outF + (size_t)NTOK * 256);
}

// Round 7
// 533.299 us; speedup vs baseline: 5.2457x; 1.0448x over previous
//
#include <hip/hip_runtime.h>
#include <math.h>

#define BB 4
#define HH 4
#define NN 2048
#define DD 256
#define HDIM 64
#define NTOK 8192
#define NTOK2 16384

typedef __attribute__((ext_vector_type(8))) __bf16 bf16x8;
typedef __attribute__((ext_vector_type(8))) unsigned short ushort8;
typedef __attribute__((ext_vector_type(4))) float floatx4;
typedef __attribute__((ext_vector_type(4))) short short4v;

union U8 { ushort8 u; bf16x8 b; };
union U4 { unsigned int u[2]; unsigned long long l; short4v s; };

// v_mfma_f32_16x16x16_bf16 (K=16): A/B = 4 bf16 (short4), C/D = 4 f32.
#define MFMA16(a, b, c) __builtin_amdgcn_mfma_f32_16x16x16bf16_1k(a, b, c, 0, 0, 0)

__device__ __forceinline__ unsigned short f2bf(float x) {
    unsigned int u = __float_as_uint(x);
    u += 0x7FFF + ((u >> 16) & 1);
    return (unsigned short)(u >> 16);
}
__device__ __forceinline__ float bf2f(unsigned short u) {
    return __uint_as_float(((unsigned int)u) << 16);
}
// round-half-up bf16 pair pack (a -> low16, b -> high16); inputs >= 0
__device__ __forceinline__ unsigned int pkbf(float a, float b) {
    return ((__float_as_uint(a) + 0x8000u) >> 16) |
           ((__float_as_uint(b) + 0x8000u) & 0xFFFF0000u);
}

// ---------------------------------------------------------------------------
// Weight transpose+convert: W[K][N] f32 -> Wt[N][K] bf16.  One dispatch, 9 segs.
// ---------------------------------------------------------------------------
struct WTab {
    const float* w[9];
    unsigned short* o[9];
    int K[9];
    int N[9];
    int t0[10];
};

__global__ __launch_bounds__(256) void wtrans(WTab tab)
{
    __shared__ float lds[32][33];
    const int t = threadIdx.x;
    int bid = blockIdx.x;
    int s = 0;
    while (bid >= tab.t0[s + 1]) s++;
    const int ti = bid - tab.t0[s];
    const int K = tab.K[s], N = tab.N[s];
    const int tx = ti % (N / 32), ty = ti / (N / 32);
    const int k0 = ty * 32, n0 = tx * 32;
    const float* W = tab.w[s];
    unsigned short* Wt = tab.o[s];

    {
        int r = t >> 3, c = (t & 7) * 4;
        float4 a = *(const float4*)&W[(size_t)(k0 + r) * N + n0 + c];
        lds[r][c] = a.x; lds[r][c+1] = a.y; lds[r][c+2] = a.z; lds[r][c+3] = a.w;
    }
    __syncthreads();
    {
        int n = t >> 3, kq = (t & 7) * 4;
        ushort4 p;
        p.x = f2bf(lds[kq+0][n]); p.y = f2bf(lds[kq+1][n]);
        p.z = f2bf(lds[kq+2][n]); p.w = f2bf(lds[kq+3][n]);
        *(ushort4*)&Wt[(size_t)(n0 + n) * K + k0 + kq] = p;
    }
}

// ---------------------------------------------------------------------------
// bf16 MFMA GEMM, 128x128 tile, register-staged double-buffered K-loop:
// global->VGPR prefetch of tile k+1 issued before compute of tile k (register
// loads legally stay in flight across s_barrier; compiler waits vmcnt only at
// the consuming ds_write, a full MFMA block later).  LDS rows padded to 40
// shorts: banks spread as (5*row+2*chunk) mod 8 -> uniform for reads+writes.
// modes: 1 bf16 row-major | 2 bf16 dual scatter (col<256 -> Q rows [bh][n][d],
//        col>=256 -> V^T [bh][d][n]) | 3 qkv scatter (V transposed) |
//        4 f32 = acc+bias+R (+ optional bf16 copies)
// ---------------------------------------------------------------------------
__global__ __launch_bounds__(256) void gemm_mfma(
    const unsigned short* __restrict__ A, int lda,
    const unsigned short* __restrict__ Wt, int K,
    const float* __restrict__ bias, const float* __restrict__ bias2, int mode,
    float* outF, unsigned short* outH0, unsigned short* outH1,
    unsigned short* outH2,
    int ldc, const float* R0, const float* R1)
{
    __shared__ __align__(16) unsigned short As[128 * 40];
    __shared__ __align__(16) unsigned short Bs[128 * 40];
    const int t = threadIdx.x;
    const int w = t >> 6, lane = t & 63, quad = lane >> 4, l15 = lane & 15;
    const int m0 = blockIdx.y * 128, n0 = blockIdx.x * 128;
    const int wm = (w >> 1) * 64, wn = (w & 1) * 64;
    const int sr = t >> 1, sc = (t & 1) * 16;

    const unsigned short* Ap = A  + (size_t)(m0 + sr) * lda + sc;
    const unsigned short* Bp = Wt + (size_t)(n0 + sr) * K   + sc;

    ushort8 pa0 = *(const ushort8*)(Ap);
    ushort8 pa1 = *(const ushort8*)(Ap + 8);
    ushort8 pb0 = *(const ushort8*)(Bp);
    ushort8 pb1 = *(const ushort8*)(Bp + 8);

    floatx4 acc[4][4];
    #pragma unroll
    for (int i = 0; i < 4; i++)
        #pragma unroll
        for (int j = 0; j < 4; j++) acc[i][j] = (floatx4){0.f, 0.f, 0.f, 0.f};

    const int nk = K >> 5;
    for (int kk = 0; kk < nk; kk++) {
        *(ushort8*)&As[sr * 40 + sc]     = pa0;
        *(ushort8*)&As[sr * 40 + sc + 8] = pa1;
        *(ushort8*)&Bs[sr * 40 + sc]     = pb0;
        *(ushort8*)&Bs[sr * 40 + sc + 8] = pb1;
        __syncthreads();
        if (kk + 1 < nk) {
            int ko = (kk + 1) * 32;
            pa0 = *(const ushort8*)(Ap + ko);
            pa1 = *(const ushort8*)(Ap + ko + 8);
            pb0 = *(const ushort8*)(Bp + ko);
            pb1 = *(const ushort8*)(Bp + ko + 8);
        }
        U8 af[4], bf[4];
        #pragma unroll
        for (int i = 0; i < 4; i++)
            af[i].u = *(const ushort8*)&As[(wm + i * 16 + l15) * 40 + quad * 8];
        #pragma unroll
        for (int j = 0; j < 4; j++)
            bf[j].u = *(const ushort8*)&Bs[(wn + j * 16 + l15) * 40 + quad * 8];
        #pragma unroll
        for (int i = 0; i < 4; i++)
            #pragma unroll
            for (int j = 0; j < 4; j++)
                acc[i][j] = __builtin_amdgcn_mfma_f32_16x16x32_bf16(af[i].b, bf[j].b, acc[i][j], 0, 0, 0);
        __syncthreads();
    }

    #pragma unroll
    for (int i = 0; i < 4; i++) {
        #pragma unroll
        for (int j = 0; j < 4; j++) {
            int col = n0 + wn + j * 16 + l15;
            float bv = (mode == 2 && col >= 256) ? bias2[col & 255] : bias[col];
            #pragma unroll
            for (int r = 0; r < 4; r++) {
                int grow = m0 + wm + i * 16 + quad * 4 + r;
                float v = acc[i][j][r] + bv;
                if (mode == 1) {
                    outH0[(size_t)grow * ldc + col] = f2bf(v);
                } else if (mode == 2) {
                    int cc = col & 255;
                    int h = cc >> 6, d = cc & 63;
                    int ds = grow >> 13, b = (grow >> 11) & 3, n = grow & 2047;
                    int bh = ds * 16 + b * 4 + h;
                    if (col < 256)
                        outH0[((size_t)bh * NN + n) * HDIM + d] = f2bf(v);
                    else  // V^T layout [bh][hd][n]
                        outH1[((size_t)bh * HDIM + d) * NN + n] = f2bf(v);
                } else if (mode == 3) {
                    int sel = col % 3, cc = col / 3;
                    int h = cc >> 6, d = cc & 63;
                    int ds = grow >> 13, b = (grow >> 11) & 3, n = grow & 2047;
                    int bh = ds * 16 + b * 4 + h;
                    if (sel == 0)
                        outH0[((size_t)bh * NN + n) * HDIM + d] = f2bf(v);
                    else if (sel == 1)
                        outH1[((size_t)bh * NN + n) * HDIM + d] = f2bf(v);
                    else  // V^T layout [bh][hd][n]
                        outH2[((size_t)bh * HDIM + d) * NN + n] = f2bf(v);
                } else {
                    const float* R = (grow < NTOK) ? R0 : R1;
                    float vv = v + R[(size_t)(grow & 8191) * 256 + col];
                    outF[(size_t)grow * 256 + col] = vv;
                    if (outH0) outH0[(size_t)grow * 256 + col] = f2bf(vv);
                    if (outH1) outH1[(size_t)grow * 512 + col] = f2bf(vv);
                }
            }
        }
    }
}

// ---------------------------------------------------------------------------
// RoPE in place on qb and kb (bf16 [32][2048][64]); enc0/enc1 f32 [2,B,1,N,HD].
// ---------------------------------------------------------------------------
__global__ __launch_bounds__(256) void rope_k(unsigned short* __restrict__ qb,
                                              unsigned short* __restrict__ kb,
                                              const float* __restrict__ enc0,
                                              const float* __restrict__ enc1)
{
    int i = blockIdx.x * 256 + threadIdx.x;     // 2^22 pair slots
    int dp = (i & 31) * 2;
    int n  = (i >> 5) & (NN - 1);
    int h  = (i >> 16) & 3;
    int b  = (i >> 18) & 3;
    int ds = (i >> 20) & 1;
    int bf = (i >> 21) & 1;
    unsigned short* tq = (bf ? kb : qb) +
        (((size_t)(ds * 16 + b * 4 + h)) * NN + n) * HDIM + dp;
    const float* e0 = (ds ? enc1 : enc0) + ((size_t)b * NN + n) * HDIM + dp;
    const float* e1 = e0 + (size_t)BB * NN * HDIM;
    float x0 = bf2f(tq[0]), x1 = bf2f(tq[1]);
    float y0 = x0 * e0[0] - x1 * e1[0];
    float y1 = x1 * e0[1] + x0 * e1[1];
    tq[0] = f2bf(y0); tq[1] = f2bf(y1);
}

// ---------------------------------------------------------------------------
// MFMA bf16 flash attention, S^T formulation.  Q,K row-major [32][2048][64];
// V PRE-TRANSPOSED [32][64][2048].  Staging = pure b128 copies with register
// prefetch of the next tile issued before compute (loads cross the barrier).
// KV head = bh ^ kvx.  O: bf16 [16384][256].  qscale includes log2(e).
// ---------------------------------------------------------------------------
__global__ __launch_bounds__(256) void flash_attn(
    const unsigned short* __restrict__ Q, const unsigned short* __restrict__ K,
    const unsigned short* __restrict__ V, unsigned short* __restrict__ O,
    int kvx, float qscale)
{
    __shared__ __align__(16) unsigned short Ks[64 * 72];    // [key][hd]
    __shared__ __align__(16) unsigned short Vt[64 * 72];    // [hd][key]

    const int t    = threadIdx.x;
    const int w    = t >> 6;
    const int lane = t & 63;
    const int quad = lane >> 4;
    const int l15  = lane & 15;
    const int bh   = blockIdx.y;
    const int kbh  = bh ^ kvx;
    const int q0   = blockIdx.x * 64;

    const unsigned short* Qb  = Q + (size_t)bh  * NN * HDIM;
    const unsigned short* Kb  = K + (size_t)kbh * NN * HDIM;
    const unsigned short* VTb = V + (size_t)kbh * NN * HDIM;   // [hd][n]

    // staging chunk coords: 64 rows x 8 chunks of 8 shorts; thread does 2 rows
    const int srf = t >> 3, scf = (t & 7) * 8;

    // Q fragments: lane l15 = q-row, k(hd) = quad*8+j  (B-operand of K·Q^T)
    const int qrow = q0 + w * 16 + l15;
    bf16x8 qf0, qf1;
    {
        U8 r0, r1, x0, x1;
        r0.u = *(const ushort8*)&Qb[(size_t)qrow * HDIM + quad * 8];
        r1.u = *(const ushort8*)&Qb[(size_t)qrow * HDIM + 32 + quad * 8];
        #pragma unroll
        for (int j = 0; j < 8; j++) {
            x0.u[j] = f2bf(bf2f(r0.u[j]) * qscale);
            x1.u[j] = f2bf(bf2f(r1.u[j]) * qscale);
        }
        qf0 = x0.b; qf1 = x1.b;
    }

    floatx4 o[4];   // O^T accumulator: col = q = l15, row(hd) = c*16 + quad*4 + r
    #pragma unroll
    for (int c = 0; c < 4; c++) o[c] = (floatx4){0.f, 0.f, 0.f, 0.f};
    float m = -1e30f, l = 0.f;

    // prefetch tile 0
    ushort8 ka0 = *(const ushort8*)&Kb[(size_t)srf * HDIM + scf];
    ushort8 ka1 = *(const ushort8*)&Kb[(size_t)(srf + 32) * HDIM + scf];
    ushort8 va0 = *(const ushort8*)&VTb[(size_t)srf * NN + scf];
    ushort8 va1 = *(const ushort8*)&VTb[(size_t)(srf + 32) * NN + scf];

    for (int j0 = 0; j0 < NN; j0 += 64) {
        *(ushort8*)&Ks[srf * 72 + scf]        = ka0;
        *(ushort8*)&Ks[(srf + 32) * 72 + scf] = ka1;
        *(ushort8*)&Vt[srf * 72 + scf]        = va0;
        *(ushort8*)&Vt[(srf + 32) * 72 + scf] = va1;
        __syncthreads();
        if (j0 + 64 < NN) {
            int jn = j0 + 64;
            ka0 = *(const ushort8*)&Kb[(size_t)(jn + srf) * HDIM + scf];
            ka1 = *(const ushort8*)&Kb[(size_t)(jn + srf + 32) * HDIM + scf];
            va0 = *(const ushort8*)&VTb[(size_t)srf * NN + jn + scf];
            va1 = *(const ushort8*)&VTb[(size_t)(srf + 32) * NN + jn + scf];
        }

        // S^T = K (qscale*Q)^T : s[t4]: col = q = l15, row(key) = quad*4 + r
        floatx4 s[4];
        #pragma unroll
        for (int t4 = 0; t4 < 4; t4++) {
            U8 k0, k1;
            k0.u = *(const ushort8*)&Ks[(t4 * 16 + l15) * 72 + quad * 8];
            k1.u = *(const ushort8*)&Ks[(t4 * 16 + l15) * 72 + 32 + quad * 8];
            floatx4 z = (floatx4){0.f, 0.f, 0.f, 0.f};
            z = __builtin_amdgcn_mfma_f32_16x16x32_bf16(k0.b, qf0, z, 0, 0, 0);
            z = __builtin_amdgcn_mfma_f32_16x16x32_bf16(k1.b, qf1, z, 0, 0, 0);
            s[t4] = z;
        }

        // per-lane online softmax (one q-row per lane; keys split across quads)
        float mx = s[0][0];
        #pragma unroll
        for (int t4 = 0; t4 < 4; t4++)
            #pragma unroll
            for (int r = 0; r < 4; r++) mx = fmaxf(mx, s[t4][r]);
        mx = fmaxf(mx, __shfl_xor(mx, 16, 64));
        mx = fmaxf(mx, __shfl_xor(mx, 32, 64));
        float mn = fmaxf(m, mx);
        float al = exp2f(m - mn);
        m = mn;
        float rs = 0.f;
        #pragma unroll
        for (int t4 = 0; t4 < 4; t4++)
            #pragma unroll
            for (int r = 0; r < 4; r++) {
                float p = exp2f(s[t4][r] - mn);
                s[t4][r] = p;
                rs += p;
            }
        rs += __shfl_xor(rs, 16, 64);
        rs += __shfl_xor(rs, 32, 64);
        l = l * al + rs;
        #pragma unroll
        for (int c = 0; c < 4; c++)
            #pragma unroll
            for (int r = 0; r < 4; r++) o[c][r] *= al;

        // pack P^T fragments: C/D layout of S^T == B-operand of 16x16x16
        short4v pf[4];
        #pragma unroll
        for (int t4 = 0; t4 < 4; t4++) {
            U4 pk;
            pk.u[0] = pkbf(s[t4][0], s[t4][1]);
            pk.u[1] = pkbf(s[t4][2], s[t4][3]);
            pf[t4] = pk.s;
        }

        // O^T += V^T P^T : A = V^T chunk [hd=c*16+l15][key=t4*16+quad*4+j]
        #pragma unroll
        for (int c = 0; c < 4; c++) {
            #pragma unroll
            for (int t4 = 0; t4 < 4; t4++) {
                U4 vf;
                vf.l = *(const unsigned long long*)
                    &Vt[(c * 16 + l15) * 72 + t4 * 16 + quad * 4];
                o[c] = MFMA16(vf.s, pf[t4], o[c]);
            }
        }
        __syncthreads();
    }

    // epilogue: normalize, write bf16 [16384][256]; lane owns q=l15, 16 hd vals
    const int ds = bh >> 4, b = (bh >> 2) & 3, h = bh & 3;
    const int q = q0 + w * 16 + l15;
    const size_t row = (size_t)ds * NTOK + b * NN + q;
    float inv = 1.f / l;
    #pragma unroll
    for (int c = 0; c < 4; c++) {
        ushort4 pk;
        pk.x = f2bf(o[c][0] * inv);
        pk.y = f2bf(o[c][1] * inv);
        pk.z = f2bf(o[c][2] * inv);
        pk.w = f2bf(o[c][3] * inv);
        *(ushort4*)&O[row * DD + h * HDIM + c * 16 + quad * 4] = pk;
    }
}

// ---------------------------------------------------------------------------
// LayerNorm + exact GELU, bf16 in-place, row width 512, one block per row.
// ---------------------------------------------------------------------------
__global__ __launch_bounds__(256) void ln_gelu(
    unsigned short* __restrict__ hb, const float* __restrict__ g,
    const float* __restrict__ be)
{
    __shared__ float r1[4], r2[4];
    const int t = threadIdx.x;
    const size_t row = blockIdx.x;
    unsigned short* ip = hb + row * 512;
    float x0 = bf2f(ip[t]), x1 = bf2f(ip[t + 256]);
    float s = x0 + x1, ss = x0 * x0 + x1 * x1;
    #pragma unroll
    for (int o = 32; o > 0; o >>= 1) { s += __shfl_down(s, o); ss += __shfl_down(ss, o); }
    if ((t & 63) == 0) { r1[t >> 6] = s; r2[t >> 6] = ss; }
    __syncthreads();
    float S  = r1[0] + r1[1] + r1[2] + r1[3];
    float SS = r2[0] + r2[1] + r2[2] + r2[3];
    float mean = S * (1.f / 512.f);
    float var  = SS * (1.f / 512.f) - mean * mean;
    float inv  = rsqrtf(var + 1e-5f);
    float y0 = (x0 - mean) * inv * g[t]       + be[t];
    float y1 = (x1 - mean) * inv * g[t + 256] + be[t + 256];
    ip[t]       = f2bf(0.5f * y0 * (1.f + erff(y0 * 0.70710678f)));
    ip[t + 256] = f2bf(0.5f * y1 * (1.f + erff(y1 * 0.70710678f)));
}

// ---------------------------------------------------------------------------
// cat[row][0:256] = desc (f32 pair) as bf16.
// ---------------------------------------------------------------------------
__global__ __launch_bounds__(256) void copy_to_cat(
    const float* __restrict__ s0, const float* __restrict__ s1,
    unsigned short* __restrict__ cat)
{
    int i = blockIdx.x * 256 + threadIdx.x;
    int row = i >> 6, c4 = (i & 63) * 4;
    const float* s = (row < NTOK) ? s0 : s1;
    float4 a = *(const float4*)&s[(size_t)(row & 8191) * 256 + c4];
    ushort4 p = { f2bf(a.x), f2bf(a.y), f2bf(a.z), f2bf(a.w) };
    *(ushort4*)&cat[(size_t)row * 512 + c4] = p;
}

// ---------------------------------------------------------------------------
extern "C" void kernel_launch(void* const* d_in, const int* in_sizes, int n_in,
                              void* d_out, int out_size, void* d_ws, size_t ws_size,
                              hipStream_t stream)
{
    const float* desc0 = (const float*)d_in[0];
    const float* desc1 = (const float*)d_in[1];
    const float* enc0  = (const float*)d_in[2];
    const float* enc1  = (const float*)d_in[3];
    const float* Wqkv  = (const float*)d_in[4];  const float* bqkv  = (const float*)d_in[5];
    const float* Wo_s  = (const float*)d_in[6];  const float* bo_s  = (const float*)d_in[7];
    const float* W1_s  = (const float*)d_in[8];  const float* b1_s  = (const float*)d_in[9];
    const float* g_s   = (const float*)d_in[10]; const float* be_s  = (const float*)d_in[11];
    const float* W2_s  = (const float*)d_in[12]; const float* b2_s  = (const float*)d_in[13];
    const float* Wqk_c = (const float*)d_in[14]; const float* bqk_c = (const float*)d_in[15];
    const float* Wv_c  = (const float*)d_in[16]; const float* bv_c  = (const float*)d_in[17];
    const float* Wo_c  = (const float*)d_in[18]; const float* bo_c  = (const float*)d_in[19];
    const float* W1_c  = (const float*)d_in[20]; const float* b1_c  = (const float*)d_in[21];
    const float* g_c   = (const float*)d_in[22]; const float* be_c  = (const float*)d_in[23];
    const float* W2_c  = (const float*)d_in[24]; const float* b2_c  = (const float*)d_in[25];

    char* ws = (char*)d_ws;
    unsigned short* wt  = (unsigned short*)ws;                      // 2,490,368 B
    unsigned short* qb  = (unsigned short*)(ws + 2490368);
    unsigned short* kb  = (unsigned short*)(ws + 10878976);
    unsigned short* msg = (unsigned short*)(ws + 19267584);
    unsigned short* vb  = (unsigned short*)(ws + 27656192);         // V^T [32][64][2048]
    unsigned short* cat = (unsigned short*)(ws + 36044800);         // 16.8 MB
    unsigned short* hb  = (unsigned short*)(ws + 52822016);         // bf16 [16384][512]
    unsigned short* dbf = (unsigned short*)(ws + 86376448);

    unsigned short* t_qkv = wt;
    unsigned short* t_wos = wt + 196608;
    unsigned short* t_w1s = wt + 262144;
    unsigned short* t_w2s = wt + 524288;
    unsigned short* t_wqk = wt + 655360;
    unsigned short* t_wv  = wt + 720896;
    unsigned short* t_woc = wt + 786432;
    unsigned short* t_w1c = wt + 851968;
    unsigned short* t_w2c = wt + 1114112;

    float* outF = (float*)d_out;   // [16384][256]

    dim3 blk(256);

    WTab tab;
    tab.w[0] = Wqkv;  tab.o[0] = t_qkv; tab.K[0] = 256; tab.N[0] = 768;
    tab.w[1] = Wo_s;  tab.o[1] = t_wos; tab.K[1] = 256; tab.N[1] = 256;
    tab.w[2] = W1_s;  tab.o[2] = t_w1s; tab.K[2] = 512; tab.N[2] = 512;
    tab.w[3] = W2_s;  tab.o[3] = t_w2s; tab.K[3] = 512; tab.N[3] = 256;
    tab.w[4] = Wqk_c; tab.o[4] = t_wqk; tab.K[4] = 256; tab.N[4] = 256;
    tab.w[5] = Wv_c;  tab.o[5] = t_wv;  tab.K[5] = 256; tab.N[5] = 256;
    tab.w[6] = Wo_c;  tab.o[6] = t_woc; tab.K[6] = 256; tab.N[6] = 256;
    tab.w[7] = W1_c;  tab.o[7] = t_w1c; tab.K[7] = 512; tab.N[7] = 512;
    tab.w[8] = W2_c;  tab.o[8] = t_w2c; tab.K[8] = 512; tab.N[8] = 256;
    int acc_t = 0;
    for (int s = 0; s < 9; s++) {
        tab.t0[s] = acc_t;
        acc_t += (tab.K[s] / 32) * (tab.N[s] / 32);
    }
    tab.t0[9] = acc_t;
    hipLaunchKernelGGL(wtrans, dim3(acc_t), blk, 0, stream, tab);

    auto gemm = [&](const unsigned short* A, int lda, const unsigned short* Wtp,
                    int K, const float* bias, const float* bias2, int Nc, int mode,
                    float* oF, unsigned short* oh0, unsigned short* oh1,
                    unsigned short* oh2, int ldc, const float* r0, const float* r1) {
        dim3 g(Nc / 128, NTOK2 / 128);
        hipLaunchKernelGGL(gemm_mfma, g, blk, 0, stream,
                           A, lda, Wtp, K, bias, bias2, mode,
                           oF, oh0, oh1, oh2, ldc, r0, r1);
    };

    const float QS = 0.125f * 1.44269504088896f;

    // ---- self block (both streams batched) ----
    hipLaunchKernelGGL(copy_to_cat, dim3(4096), blk, 0, stream, desc0, desc1, cat);
    gemm(cat, 512, t_qkv, 256, bqkv, nullptr, 768, 3,
         nullptr, qb, kb, vb, 0, nullptr, nullptr);
    hipLaunchKernelGGL(rope_k, dim3(16384), blk, 0, stream, qb, kb, enc0, enc1);
    hipLaunchKernelGGL(flash_attn, dim3(NN / 64, 32), blk, 0, stream,
                       qb, kb, vb, msg, 0, QS);
    gemm(msg, 256, t_wos, 256, bo_s, nullptr, 256, 1,
         nullptr, cat + 256, nullptr, nullptr, 512, nullptr, nullptr);
    gemm(cat, 512, t_w1s, 512, b1_s, nullptr, 512, 1,
         nullptr, hb, nullptr, nullptr, 512, nullptr, nullptr);
    hipLaunchKernelGGL(ln_gelu, dim3(NTOK2), blk, 0, stream, hb, g_s, be_s);
    gemm(hb, 512, t_w2s, 512, b2_s, nullptr, 256, 4,
         outF, dbf, cat, nullptr, 256, desc0, desc1);

    // ---- cross block ----
    gemm(dbf, 256, t_wqk, 256, bqk_c, bv_c, 512, 2,
         nullptr, qb, vb, nullptr, 0, nullptr, nullptr);
    hipLaunchKernelGGL(flash_attn, dim3(NN / 64, 32), blk, 0, stream,
                       qb, qb, vb, msg, 16, QS);
    gemm(msg, 256, t_woc, 256, bo_c, nullptr, 256, 1,
         nullptr, cat + 256, nullptr, nullptr, 512, nullptr, nullptr);
    gemm(cat, 512, t_w1c, 512, b1_c, nullptr, 512, 1,
         nullptr, hb, nullptr, nullptr, 512, nullptr, nullptr);
    hipLaunchKernelGGL(ln_gelu, dim3(NTOK2), blk, 0, stream, hb, g_c, be_c);
    gemm(hb, 512, t_w2c, 512, b2_c, nullptr, 256, 4,
         outF, nullptr, nullptr, nullptr, 256, outF, outF + (size_t)NTOK * 256);
}

// Round 8
// 494.205 us; speedup vs baseline: 5.6607x; 1.0791x over previous
//
#include <hip/hip_runtime.h>
#include <math.h>

#define BB 4
#define HH 4
#define NN 2048
#define DD 256
#define HDIM 64
#define NTOK 8192
#define NTOK2 16384

typedef __attribute__((ext_vector_type(8))) __bf16 bf16x8;
typedef __attribute__((ext_vector_type(8))) unsigned short ushort8;
typedef __attribute__((ext_vector_type(4))) float floatx4;
typedef __attribute__((ext_vector_type(4))) short short4v;

union U8 { ushort8 u; bf16x8 b; };
union U4 { unsigned int u[2]; unsigned long long l; short4v s; };

// v_mfma_f32_16x16x16_bf16 (K=16): A/B = 4 bf16 (short4), C/D = 4 f32.
#define MFMA16(a, b, c) __builtin_amdgcn_mfma_f32_16x16x16bf16_1k(a, b, c, 0, 0, 0)

__device__ __forceinline__ unsigned short f2bf(float x) {
    unsigned int u = __float_as_uint(x);
    u += 0x7FFF + ((u >> 16) & 1);
    return (unsigned short)(u >> 16);
}
__device__ __forceinline__ float bf2f(unsigned short u) {
    return __uint_as_float(((unsigned int)u) << 16);
}
// round-half-up bf16 pair pack (a -> low16, b -> high16); inputs >= 0
__device__ __forceinline__ unsigned int pkbf(float a, float b) {
    return ((__float_as_uint(a) + 0x8000u) >> 16) |
           ((__float_as_uint(b) + 0x8000u) & 0xFFFF0000u);
}

// ---------------------------------------------------------------------------
// Weight transpose+convert: W[K][N] f32 -> Wt[N][st] bf16 (st = output row
// stride in k; lets W1 top-halves land in 512-stride composite buffers).
// ---------------------------------------------------------------------------
struct WTab {
    const float* w[7];
    unsigned short* o[7];
    int K[7];
    int N[7];
    int st[7];
    int t0[8];
};

__global__ __launch_bounds__(256) void wtrans(WTab tab)
{
    __shared__ float lds[32][33];
    const int t = threadIdx.x;
    int bid = blockIdx.x;
    int s = 0;
    while (bid >= tab.t0[s + 1]) s++;
    const int ti = bid - tab.t0[s];
    const int K = tab.K[s], N = tab.N[s], st = tab.st[s];
    const int tx = ti % (N / 32), ty = ti / (N / 32);
    const int k0 = ty * 32, n0 = tx * 32;
    const float* W = tab.w[s];
    unsigned short* Wt = tab.o[s];

    {
        int r = t >> 3, c = (t & 7) * 4;
        float4 a = *(const float4*)&W[(size_t)(k0 + r) * N + n0 + c];
        lds[r][c] = a.x; lds[r][c+1] = a.y; lds[r][c+2] = a.z; lds[r][c+3] = a.w;
    }
    __syncthreads();
    {
        int n = t >> 3, kq = (t & 7) * 4;
        ushort4 p;
        p.x = f2bf(lds[kq+0][n]); p.y = f2bf(lds[kq+1][n]);
        p.z = f2bf(lds[kq+2][n]); p.w = f2bf(lds[kq+3][n]);
        *(ushort4*)&Wt[(size_t)(n0 + n) * st + k0 + kq] = p;
    }
}

// ---------------------------------------------------------------------------
// Weight fusion: Weff_bot[i][n] = sum_j Wo[i][j] * W1[256+j][n], written
// transposed-bf16 into out[n][256+i] (512-stride).  grid 128: seg = bid>>6.
// ---------------------------------------------------------------------------
__global__ __launch_bounds__(256) void wfuse(
    const float* __restrict__ Wo_s, const float* __restrict__ W1_s,
    unsigned short* __restrict__ o_s,
    const float* __restrict__ Wo_c, const float* __restrict__ W1_c,
    unsigned short* __restrict__ o_c)
{
    __shared__ float wo[32][33];
    __shared__ float w1[32][68];
    const int t = threadIdx.x;
    const int bid = blockIdx.x;
    const int seg = bid >> 6, ti_ = bid & 63;
    const int i0 = (ti_ >> 3) * 32, n0 = (ti_ & 7) * 64;
    const float* Wo  = seg ? Wo_c : Wo_s;
    const float* W1b = (seg ? W1_c : W1_s) + 256 * 512;
    unsigned short* out = seg ? o_c : o_s;
    const int ti = t >> 3, tn = t & 7;

    float acc[8] = {};
    for (int jc = 0; jc < 256; jc += 32) {
        {
            int r = t >> 3, c = (t & 7) * 4;
            *(float4*)&wo[r][c] = *(const float4*)&Wo[(size_t)(i0 + r) * 256 + jc + c];
            int c8 = (t & 7) * 8;
            *(float4*)&w1[r][c8]     = *(const float4*)&W1b[(size_t)(jc + r) * 512 + n0 + c8];
            *(float4*)&w1[r][c8 + 4] = *(const float4*)&W1b[(size_t)(jc + r) * 512 + n0 + c8 + 4];
        }
        __syncthreads();
        #pragma unroll
        for (int j = 0; j < 32; j++) {
            float a = wo[ti][j];
            #pragma unroll
            for (int e = 0; e < 8; e++) acc[e] += a * w1[j][tn * 8 + e];
        }
        __syncthreads();
    }
    #pragma unroll
    for (int e = 0; e < 8; e++)
        out[(size_t)(n0 + tn * 8 + e) * 512 + 256 + i0 + ti] = f2bf(acc[e]);
}

// ---------------------------------------------------------------------------
// Bias fusion: beff[n] = b1[n] + sum_j bo[j] * W1[256+j][n].  grid 4.
// ---------------------------------------------------------------------------
__global__ __launch_bounds__(256) void bfuse(
    const float* bo_s, const float* W1_s, const float* b1_s, float* bs,
    const float* bo_c, const float* W1_c, const float* b1_c, float* bc)
{
    const int seg = blockIdx.x >> 1, half = blockIdx.x & 1;
    const int n = half * 256 + threadIdx.x;
    const float* bo  = seg ? bo_c : bo_s;
    const float* W1b = (seg ? W1_c : W1_s) + 256 * 512;
    const float* b1  = seg ? b1_c : b1_s;
    float* out       = seg ? bc : bs;
    float a = b1[n];
    for (int j = 0; j < 256; j++) a += bo[j] * W1b[(size_t)j * 512 + n];
    out[n] = a;
}

// ---------------------------------------------------------------------------
// bf16 MFMA GEMM, 64x128 tile (grid 2-6 blocks/CU for latency hiding),
// register-staged double-buffered K-loop, LDS rows padded to 40 shorts.
// modes: 1 bf16 row-major | 2 bf16 dual scatter (col<256 -> rows [bh][n][d],
//        col>=256 -> V^T [bh][d][n]) | 3 qkv scatter (V transposed) |
//        4 f32 = acc+bias+R (+ bf16 copies to outH0 [.,256] / outH1 [.,512])
// ---------------------------------------------------------------------------
__global__ __launch_bounds__(256) void gemm_mfma(
    const unsigned short* __restrict__ A, int lda,
    const unsigned short* __restrict__ Wt, int K,
    const float* __restrict__ bias, const float* __restrict__ bias2, int mode,
    float* outF, unsigned short* outH0, unsigned short* outH1,
    unsigned short* outH2,
    int ldc, const float* R0, const float* R1)
{
    __shared__ __align__(16) unsigned short As[64 * 40];
    __shared__ __align__(16) unsigned short Bs[128 * 40];
    const int t = threadIdx.x;
    const int w = t >> 6, lane = t & 63, quad = lane >> 4, l15 = lane & 15;
    const int m0 = blockIdx.y * 64, n0 = blockIdx.x * 128;
    const int wn = w * 32;
    const int sar = t >> 2, sac = (t & 3) * 8;
    const int sbr = t >> 1, sbc = (t & 1) * 16;

    const unsigned short* Ap = A  + (size_t)(m0 + sar) * lda + sac;
    const unsigned short* Bp = Wt + (size_t)(n0 + sbr) * K   + sbc;

    ushort8 pa  = *(const ushort8*)(Ap);
    ushort8 pb0 = *(const ushort8*)(Bp);
    ushort8 pb1 = *(const ushort8*)(Bp + 8);

    floatx4 acc[4][2];
    #pragma unroll
    for (int i = 0; i < 4; i++)
        #pragma unroll
        for (int j = 0; j < 2; j++) acc[i][j] = (floatx4){0.f, 0.f, 0.f, 0.f};

    const int nk = K >> 5;
    for (int kk = 0; kk < nk; kk++) {
        *(ushort8*)&As[sar * 40 + sac]     = pa;
        *(ushort8*)&Bs[sbr * 40 + sbc]     = pb0;
        *(ushort8*)&Bs[sbr * 40 + sbc + 8] = pb1;
        __syncthreads();
        if (kk + 1 < nk) {
            int ko = (kk + 1) * 32;
            pa  = *(const ushort8*)(Ap + ko);
            pb0 = *(const ushort8*)(Bp + ko);
            pb1 = *(const ushort8*)(Bp + ko + 8);
        }
        U8 af[4], bf[2];
        #pragma unroll
        for (int i = 0; i < 4; i++)
            af[i].u = *(const ushort8*)&As[(i * 16 + l15) * 40 + quad * 8];
        #pragma unroll
        for (int j = 0; j < 2; j++)
            bf[j].u = *(const ushort8*)&Bs[(wn + j * 16 + l15) * 40 + quad * 8];
        #pragma unroll
        for (int i = 0; i < 4; i++)
            #pragma unroll
            for (int j = 0; j < 2; j++)
                acc[i][j] = __builtin_amdgcn_mfma_f32_16x16x32_bf16(af[i].b, bf[j].b, acc[i][j], 0, 0, 0);
        __syncthreads();
    }

    #pragma unroll
    for (int i = 0; i < 4; i++) {
        #pragma unroll
        for (int j = 0; j < 2; j++) {
            int col = n0 + wn + j * 16 + l15;
            float bv = (mode == 2 && col >= 256) ? bias2[col & 255] : bias[col];
            #pragma unroll
            for (int r = 0; r < 4; r++) {
                int grow = m0 + i * 16 + quad * 4 + r;
                float v = acc[i][j][r] + bv;
                if (mode == 1) {
                    outH0[(size_t)grow * ldc + col] = f2bf(v);
                } else if (mode == 2) {
                    int cc = col & 255;
                    int h = cc >> 6, d = cc & 63;
                    int ds = grow >> 13, b = (grow >> 11) & 3, n = grow & 2047;
                    int bh = ds * 16 + b * 4 + h;
                    if (col < 256)
                        outH0[((size_t)bh * NN + n) * HDIM + d] = f2bf(v);
                    else  // V^T layout [bh][hd][n]
                        outH1[((size_t)bh * HDIM + d) * NN + n] = f2bf(v);
                } else if (mode == 3) {
                    int sel = col % 3, cc = col / 3;
                    int h = cc >> 6, d = cc & 63;
                    int ds = grow >> 13, b = (grow >> 11) & 3, n = grow & 2047;
                    int bh = ds * 16 + b * 4 + h;
                    if (sel == 0)
                        outH0[((size_t)bh * NN + n) * HDIM + d] = f2bf(v);
                    else if (sel == 1)
                        outH1[((size_t)bh * NN + n) * HDIM + d] = f2bf(v);
                    else  // V^T layout [bh][hd][n]
                        outH2[((size_t)bh * HDIM + d) * NN + n] = f2bf(v);
                } else {
                    const float* R = (grow < NTOK) ? R0 : R1;
                    float vv = v + R[(size_t)(grow & 8191) * 256 + col];
                    outF[(size_t)grow * 256 + col] = vv;
                    if (outH0) outH0[(size_t)grow * 256 + col] = f2bf(vv);
                    if (outH1) outH1[(size_t)grow * 512 + col] = f2bf(vv);
                }
            }
        }
    }
}

// ---------------------------------------------------------------------------
// RoPE in place on qb and kb (bf16 [32][2048][64]); enc0/enc1 f32 [2,B,1,N,HD].
// ---------------------------------------------------------------------------
__global__ __launch_bounds__(256) void rope_k(unsigned short* __restrict__ qb,
                                              unsigned short* __restrict__ kb,
                                              const float* __restrict__ enc0,
                                              const float* __restrict__ enc1)
{
    int i = blockIdx.x * 256 + threadIdx.x;     // 2^22 pair slots
    int dp = (i & 31) * 2;
    int n  = (i >> 5) & (NN - 1);
    int h  = (i >> 16) & 3;
    int b  = (i >> 18) & 3;
    int ds = (i >> 20) & 1;
    int bf = (i >> 21) & 1;
    unsigned short* tq = (bf ? kb : qb) +
        (((size_t)(ds * 16 + b * 4 + h)) * NN + n) * HDIM + dp;
    const float* e0 = (ds ? enc1 : enc0) + ((size_t)b * NN + n) * HDIM + dp;
    const float* e1 = e0 + (size_t)BB * NN * HDIM;
    float x0 = bf2f(tq[0]), x1 = bf2f(tq[1]);
    float y0 = x0 * e0[0] - x1 * e1[0];
    float y1 = x1 * e0[1] + x0 * e1[1];
    tq[0] = f2bf(y0); tq[1] = f2bf(y1);
}

// ---------------------------------------------------------------------------
// MFMA bf16 flash attention, S^T formulation.  Q,K row-major [32][2048][64];
// V PRE-TRANSPOSED [32][64][2048].  Staging = pure b128 copies with register
// prefetch.  KV head = bh ^ kvx.  O written bf16 at row stride ldo (writes
// straight into the concat buffer).  qscale includes log2(e).
// ---------------------------------------------------------------------------
__global__ __launch_bounds__(256) void flash_attn(
    const unsigned short* __restrict__ Q, const unsigned short* __restrict__ K,
    const unsigned short* __restrict__ V, unsigned short* __restrict__ O,
    int ldo, int kvx, float qscale)
{
    __shared__ __align__(16) unsigned short Ks[64 * 72];    // [key][hd]
    __shared__ __align__(16) unsigned short Vt[64 * 72];    // [hd][key]

    const int t    = threadIdx.x;
    const int w    = t >> 6;
    const int lane = t & 63;
    const int quad = lane >> 4;
    const int l15  = lane & 15;
    const int bh   = blockIdx.y;
    const int kbh  = bh ^ kvx;
    const int q0   = blockIdx.x * 64;

    const unsigned short* Qb  = Q + (size_t)bh  * NN * HDIM;
    const unsigned short* Kb  = K + (size_t)kbh * NN * HDIM;
    const unsigned short* VTb = V + (size_t)kbh * NN * HDIM;   // [hd][n]

    const int srf = t >> 3, scf = (t & 7) * 8;

    // Q fragments: lane l15 = q-row, k(hd) = quad*8+j  (B-operand of K·Q^T)
    const int qrow = q0 + w * 16 + l15;
    bf16x8 qf0, qf1;
    {
        U8 r0, r1, x0, x1;
        r0.u = *(const ushort8*)&Qb[(size_t)qrow * HDIM + quad * 8];
        r1.u = *(const ushort8*)&Qb[(size_t)qrow * HDIM + 32 + quad * 8];
        #pragma unroll
        for (int j = 0; j < 8; j++) {
            x0.u[j] = f2bf(bf2f(r0.u[j]) * qscale);
            x1.u[j] = f2bf(bf2f(r1.u[j]) * qscale);
        }
        qf0 = x0.b; qf1 = x1.b;
    }

    floatx4 o[4];   // O^T accumulator: col = q = l15, row(hd) = c*16 + quad*4 + r
    #pragma unroll
    for (int c = 0; c < 4; c++) o[c] = (floatx4){0.f, 0.f, 0.f, 0.f};
    float m = -1e30f, l = 0.f;

    // prefetch tile 0
    ushort8 ka0 = *(const ushort8*)&Kb[(size_t)srf * HDIM + scf];
    ushort8 ka1 = *(const ushort8*)&Kb[(size_t)(srf + 32) * HDIM + scf];
    ushort8 va0 = *(const ushort8*)&VTb[(size_t)srf * NN + scf];
    ushort8 va1 = *(const ushort8*)&VTb[(size_t)(srf + 32) * NN + scf];

    for (int j0 = 0; j0 < NN; j0 += 64) {
        *(ushort8*)&Ks[srf * 72 + scf]        = ka0;
        *(ushort8*)&Ks[(srf + 32) * 72 + scf] = ka1;
        *(ushort8*)&Vt[srf * 72 + scf]        = va0;
        *(ushort8*)&Vt[(srf + 32) * 72 + scf] = va1;
        __syncthreads();
        if (j0 + 64 < NN) {
            int jn = j0 + 64;
            ka0 = *(const ushort8*)&Kb[(size_t)(jn + srf) * HDIM + scf];
            ka1 = *(const ushort8*)&Kb[(size_t)(jn + srf + 32) * HDIM + scf];
            va0 = *(const ushort8*)&VTb[(size_t)srf * NN + jn + scf];
            va1 = *(const ushort8*)&VTb[(size_t)(srf + 32) * NN + jn + scf];
        }

        // S^T = K (qscale*Q)^T : s[t4]: col = q = l15, row(key) = quad*4 + r
        floatx4 s[4];
        #pragma unroll
        for (int t4 = 0; t4 < 4; t4++) {
            U8 k0, k1;
            k0.u = *(const ushort8*)&Ks[(t4 * 16 + l15) * 72 + quad * 8];
            k1.u = *(const ushort8*)&Ks[(t4 * 16 + l15) * 72 + 32 + quad * 8];
            floatx4 z = (floatx4){0.f, 0.f, 0.f, 0.f};
            z = __builtin_amdgcn_mfma_f32_16x16x32_bf16(k0.b, qf0, z, 0, 0, 0);
            z = __builtin_amdgcn_mfma_f32_16x16x32_bf16(k1.b, qf1, z, 0, 0, 0);
            s[t4] = z;
        }

        // per-lane online softmax (one q-row per lane; keys split across quads)
        float mx = s[0][0];
        #pragma unroll
        for (int t4 = 0; t4 < 4; t4++)
            #pragma unroll
            for (int r = 0; r < 4; r++) mx = fmaxf(mx, s[t4][r]);
        mx = fmaxf(mx, __shfl_xor(mx, 16, 64));
        mx = fmaxf(mx, __shfl_xor(mx, 32, 64));
        float mn = fmaxf(m, mx);
        float al = exp2f(m - mn);
        m = mn;
        float rs = 0.f;
        #pragma unroll
        for (int t4 = 0; t4 < 4; t4++)
            #pragma unroll
            for (int r = 0; r < 4; r++) {
                float p = exp2f(s[t4][r] - mn);
                s[t4][r] = p;
                rs += p;
            }
        rs += __shfl_xor(rs, 16, 64);
        rs += __shfl_xor(rs, 32, 64);
        l = l * al + rs;
        #pragma unroll
        for (int c = 0; c < 4; c++)
            #pragma unroll
            for (int r = 0; r < 4; r++) o[c][r] *= al;

        // pack P^T fragments: C/D layout of S^T == B-operand of 16x16x16
        short4v pf[4];
        #pragma unroll
        for (int t4 = 0; t4 < 4; t4++) {
            U4 pk;
            pk.u[0] = pkbf(s[t4][0], s[t4][1]);
            pk.u[1] = pkbf(s[t4][2], s[t4][3]);
            pf[t4] = pk.s;
        }

        // O^T += V^T P^T : A = V^T chunk [hd=c*16+l15][key=t4*16+quad*4+j]
        #pragma unroll
        for (int c = 0; c < 4; c++) {
            #pragma unroll
            for (int t4 = 0; t4 < 4; t4++) {
                U4 vf;
                vf.l = *(const unsigned long long*)
                    &Vt[(c * 16 + l15) * 72 + t4 * 16 + quad * 4];
                o[c] = MFMA16(vf.s, pf[t4], o[c]);
            }
        }
        __syncthreads();
    }

    // epilogue: normalize, write bf16 at stride ldo; lane owns q=l15, 16 hd
    const int ds = bh >> 4, b = (bh >> 2) & 3, h = bh & 3;
    const int q = q0 + w * 16 + l15;
    const size_t row = (size_t)ds * NTOK + b * NN + q;
    float inv = 1.f / l;
    #pragma unroll
    for (int c = 0; c < 4; c++) {
        ushort4 pk;
        pk.x = f2bf(o[c][0] * inv);
        pk.y = f2bf(o[c][1] * inv);
        pk.z = f2bf(o[c][2] * inv);
        pk.w = f2bf(o[c][3] * inv);
        *(ushort4*)&O[row * ldo + h * HDIM + c * 16 + quad * 4] = pk;
    }
}

// ---------------------------------------------------------------------------
// LayerNorm + exact GELU, bf16 in-place, row width 512, one block per row.
// ---------------------------------------------------------------------------
__global__ __launch_bounds__(256) void ln_gelu(
    unsigned short* __restrict__ hb, const float* __restrict__ g,
    const float* __restrict__ be)
{
    __shared__ float r1[4], r2[4];
    const int t = threadIdx.x;
    const size_t row = blockIdx.x;
    unsigned short* ip = hb + row * 512;
    float x0 = bf2f(ip[t]), x1 = bf2f(ip[t + 256]);
    float s = x0 + x1, ss = x0 * x0 + x1 * x1;
    #pragma unroll
    for (int o = 32; o > 0; o >>= 1) { s += __shfl_down(s, o); ss += __shfl_down(ss, o); }
    if ((t & 63) == 0) { r1[t >> 6] = s; r2[t >> 6] = ss; }
    __syncthreads();
    float S  = r1[0] + r1[1] + r1[2] + r1[3];
    float SS = r2[0] + r2[1] + r2[2] + r2[3];
    float mean = S * (1.f / 512.f);
    float var  = SS * (1.f / 512.f) - mean * mean;
    float inv  = rsqrtf(var + 1e-5f);
    float y0 = (x0 - mean) * inv * g[t]       + be[t];
    float y1 = (x1 - mean) * inv * g[t + 256] + be[t + 256];
    ip[t]       = f2bf(0.5f * y0 * (1.f + erff(y0 * 0.70710678f)));
    ip[t + 256] = f2bf(0.5f * y1 * (1.f + erff(y1 * 0.70710678f)));
}

// ---------------------------------------------------------------------------
// cat[row][0:256] = desc (f32 pair) as bf16.
// ---------------------------------------------------------------------------
__global__ __launch_bounds__(256) void copy_to_cat(
    const float* __restrict__ s0, const float* __restrict__ s1,
    unsigned short* __restrict__ cat)
{
    int i = blockIdx.x * 256 + threadIdx.x;
    int row = i >> 6, c4 = (i & 63) * 4;
    const float* s = (row < NTOK) ? s0 : s1;
    float4 a = *(const float4*)&s[(size_t)(row & 8191) * 256 + c4];
    ushort4 p = { f2bf(a.x), f2bf(a.y), f2bf(a.z), f2bf(a.w) };
    *(ushort4*)&cat[(size_t)row * 512 + c4] = p;
}

// ---------------------------------------------------------------------------
extern "C" void kernel_launch(void* const* d_in, const int* in_sizes, int n_in,
                              void* d_out, int out_size, void* d_ws, size_t ws_size,
                              hipStream_t stream)
{
    const float* desc0 = (const float*)d_in[0];
    const float* desc1 = (const float*)d_in[1];
    const float* enc0  = (const float*)d_in[2];
    const float* enc1  = (const float*)d_in[3];
    const float* Wqkv  = (const float*)d_in[4];  const float* bqkv  = (const float*)d_in[5];
    const float* Wo_s  = (const float*)d_in[6];  const float* bo_s  = (const float*)d_in[7];
    const float* W1_s  = (const float*)d_in[8];  const float* b1_s  = (const float*)d_in[9];
    const float* g_s   = (const float*)d_in[10]; const float* be_s  = (const float*)d_in[11];
    const float* W2_s  = (const float*)d_in[12]; const float* b2_s  = (const float*)d_in[13];
    const float* Wqk_c = (const float*)d_in[14]; const float* bqk_c = (const float*)d_in[15];
    const float* Wv_c  = (const float*)d_in[16]; const float* bv_c  = (const float*)d_in[17];
    const float* Wo_c  = (const float*)d_in[18]; const float* bo_c  = (const float*)d_in[19];
    const float* W1_c  = (const float*)d_in[20]; const float* b1_c  = (const float*)d_in[21];
    const float* g_c   = (const float*)d_in[22]; const float* be_c  = (const float*)d_in[23];
    const float* W2_c  = (const float*)d_in[24]; const float* b2_c  = (const float*)d_in[25];

    char* ws = (char*)d_ws;
    unsigned short* wt  = (unsigned short*)ws;
    unsigned short* qb  = (unsigned short*)(ws + 2490368);
    unsigned short* kb  = (unsigned short*)(ws + 10878976);
    unsigned short* vb  = (unsigned short*)(ws + 27656192);         // V^T [32][64][2048]
    unsigned short* cat = (unsigned short*)(ws + 36044800);         // bf16 [16384][512]
    unsigned short* hb  = (unsigned short*)(ws + 52822016);         // bf16 [16384][512]
    unsigned short* dbf = (unsigned short*)(ws + 86376448);         // bf16 [16384][256]

    // composite-weight regions (shorts offsets into wt)
    unsigned short* t_qkv  = wt;                 // [768][256]
    float*          bias_s = (float*)(wt + 196608);   // 512 f32
    unsigned short* t_w1s  = wt + 262144;        // [512][512] composite
    unsigned short* t_w2s  = wt + 524288;        // [256][512]
    unsigned short* t_wqkc = wt + 655360;        // [512][256] (wqk rows + wv rows)
    float*          bias_c = (float*)(wt + 786432);   // 512 f32
    unsigned short* t_w1c  = wt + 851968;        // [512][512] composite
    unsigned short* t_w2c  = wt + 1114112;       // [256][512]

    float* outF = (float*)d_out;   // [16384][256]

    dim3 blk(256);

    // ---- prep: transpose/convert + weight-space Wo fusion ----
    WTab tab;
    tab.w[0] = Wqkv;  tab.o[0] = t_qkv;          tab.K[0] = 256; tab.N[0] = 768; tab.st[0] = 256;
    tab.w[1] = W1_s;  tab.o[1] = t_w1s;          tab.K[1] = 256; tab.N[1] = 512; tab.st[1] = 512;
    tab.w[2] = W2_s;  tab.o[2] = t_w2s;          tab.K[2] = 512; tab.N[2] = 256; tab.st[2] = 512;
    tab.w[3] = Wqk_c; tab.o[3] = t_wqkc;         tab.K[3] = 256; tab.N[3] = 256; tab.st[3] = 256;
    tab.w[4] = Wv_c;  tab.o[4] = t_wqkc + 65536; tab.K[4] = 256; tab.N[4] = 256; tab.st[4] = 256;
    tab.w[5] = W1_c;  tab.o[5] = t_w1c;          tab.K[5] = 256; tab.N[5] = 512; tab.st[5] = 512;
    tab.w[6] = W2_c;  tab.o[6] = t_w2c;          tab.K[6] = 512; tab.N[6] = 256; tab.st[6] = 512;
    int acc_t = 0;
    for (int s = 0; s < 7; s++) {
        tab.t0[s] = acc_t;
        acc_t += (tab.K[s] / 32) * (tab.N[s] / 32);
    }
    tab.t0[7] = acc_t;
    hipLaunchKernelGGL(wtrans, dim3(acc_t), blk, 0, stream, tab);
    hipLaunchKernelGGL(wfuse, dim3(128), blk, 0, stream,
                       Wo_s, W1_s, t_w1s, Wo_c, W1_c, t_w1c);
    hipLaunchKernelGGL(bfuse, dim3(4), blk, 0, stream,
                       bo_s, W1_s, b1_s, bias_s, bo_c, W1_c, b1_c, bias_c);

    auto gemm = [&](const unsigned short* A, int lda, const unsigned short* Wtp,
                    int K, const float* bias, const float* bias2, int Nc, int mode,
                    float* oF, unsigned short* oh0, unsigned short* oh1,
                    unsigned short* oh2, int ldc, const float* r0, const float* r1) {
        dim3 g(Nc / 128, NTOK2 / 64);
        hipLaunchKernelGGL(gemm_mfma, g, blk, 0, stream,
                           A, lda, Wtp, K, bias, bias2, mode,
                           oF, oh0, oh1, oh2, ldc, r0, r1);
    };

    const float QS = 0.125f * 1.44269504088896f;

    // ---- self block (both streams batched) ----
    hipLaunchKernelGGL(copy_to_cat, dim3(4096), blk, 0, stream, desc0, desc1, cat);
    gemm(cat, 512, t_qkv, 256, bqkv, nullptr, 768, 3,
         nullptr, qb, kb, vb, 0, nullptr, nullptr);
    hipLaunchKernelGGL(rope_k, dim3(16384), blk, 0, stream, qb, kb, enc0, enc1);
    hipLaunchKernelGGL(flash_attn, dim3(NN / 64, 32), blk, 0, stream,
                       qb, kb, vb, cat + 256, 512, 0, QS);
    gemm(cat, 512, t_w1s, 512, bias_s, nullptr, 512, 1,
         nullptr, hb, nullptr, nullptr, 512, nullptr, nullptr);
    hipLaunchKernelGGL(ln_gelu, dim3(NTOK2), blk, 0, stream, hb, g_s, be_s);
    gemm(hb, 512, t_w2s, 512, b2_s, nullptr, 256, 4,
         outF, dbf, cat, nullptr, 256, desc0, desc1);

    // ---- cross block ----
    gemm(dbf, 256, t_wqkc, 256, bqk_c, bv_c, 512, 2,
         nullptr, qb, vb, nullptr, 0, nullptr, nullptr);
    hipLaunchKernelGGL(flash_attn, dim3(NN / 64, 32), blk, 0, stream,
                       qb, qb, vb, cat + 256, 512, 16, QS);
    gemm(cat, 512, t_w1c, 512, bias_c, nullptr, 512, 1,
         nullptr, hb, nullptr, nullptr, 512, nullptr, nullptr);
    hipLaunchKernelGGL(ln_gelu, dim3(NTOK2), blk, 0, stream, hb, g_c, be_c);
    gemm(hb, 512, t_w2c, 512, b2_c, nullptr, 256, 4,
         outF, nullptr, nullptr, nullptr, 256, outF, outF + (size_t)NTOK * 256);
}